// Round 4
// baseline (573.933 us; speedup 1.0000x reference)
//
#include <hip/hip_runtime.h>
#include <math.h>

// ---------------------------------------------------------------------------
// DynamicGNN: GCN -> SAGE(mean) -> GAT(1 head) -> GCN(128->64)
// N=50000, E=1.6M, D=128, OUT=64.
// v16: degree-sorted rank-indexed pipeline. Counting-sort nodes by in-degree
//      (512-bin hist in csr_k -> scan -> rank/perm -> CSR repack w/ rank
//      translation). All intermediates rank-indexed => waves process
//      equal-degree nodes (no divergence), contiguous lockstep srcs/ew reads
//      (L1-hot, no LDS/no barrier), coalesced writes. Keeps channel-blocked
//      [cb][N][32] H + XCD slice pinning (v14) + packed f32x2 math (v15).
//      Perm bridges: layer-1 GEMM A-read, final gather output scatter.
//      16 dispatches total.
// ---------------------------------------------------------------------------

#define BUCKET_BITS 8
#define BUCKET_SZ   256
#define NBMAX       256
#define CAP         10240   // padded bucket capacity (~8163 +- 90 expected)
#define DMAX        512     // degree histogram bins (Poisson(32): max ~70)

typedef short short8 __attribute__((ext_vector_type(8)));
typedef float f32x4 __attribute__((ext_vector_type(4)));
typedef float f32x2 __attribute__((ext_vector_type(2)));
typedef unsigned int u32x4 __attribute__((ext_vector_type(4)));
typedef unsigned short u16x8 __attribute__((ext_vector_type(8)));
typedef int int4a __attribute__((ext_vector_type(4), aligned(4)));
typedef float float4a __attribute__((ext_vector_type(4), aligned(4)));

__device__ __forceinline__ float leaky02(float x) { return x > 0.0f ? x : 0.2f * x; }
__device__ __forceinline__ float bflo(unsigned u) { return __uint_as_float(u << 16); }
__device__ __forceinline__ float bfhi(unsigned u) { return __uint_as_float(u & 0xFFFF0000u); }
__device__ __forceinline__ unsigned short f2bf(float f) {
    unsigned u = __float_as_uint(f);
    u += 0x7FFFu + ((u >> 16) & 1u);   // round-to-nearest-even
    return (unsigned short)(u >> 16);
}

// ---------------- MFMA GEMM: C16 = bf16( scale? * (A@W (+A1@W1)) + bias )
// 256 thr = 4 waves; block = 64 rows; wave = 16 rows x NO cols.
// bf16 A tensors are channel-blocked [kb][n][32] (rank-indexed); fp32 A
// (layer 1) is node-major, read via perm when PERM. C16 written blocked.
template<int NO, bool AFP32, bool SCALE, bool BIASRELU, bool DUAL, bool DOTS, bool PERM>
__global__ __launch_bounds__(256) void mgemm_k(
    const void* __restrict__ Av, const float* __restrict__ W,
    const void* __restrict__ A1v, const float* __restrict__ W1,
    unsigned short* __restrict__ C16,
    const float* __restrict__ scale, const float* __restrict__ bias,
    const float* __restrict__ a_s, const float* __restrict__ a_d,
    float* __restrict__ as_, float* __restrict__ ad_,
    const int* __restrict__ permp, int n)
{
    constexpr int CT = NO / 16;
    __shared__ unsigned short Wp[128 * NO];   // packed B-frags (32/16 KB)
    const int tid = threadIdx.x;
    const int wave = tid >> 6, lane = tid & 63;
    const int q = lane >> 4, ml = lane & 15;
    const int row0 = blockIdx.x * 64 + wave * 16;
    int arow = row0 + ml; if (arow >= n) arow = n - 1;
    const int prow = (AFP32 && PERM) ? permp[arow] : arow;

    f32x4 acc[CT];
#pragma unroll
    for (int c = 0; c < CT; c++) acc[c] = {0.f, 0.f, 0.f, 0.f};

    for (int half = 0; half < (DUAL ? 2 : 1); half++) {
        const float* Wsrc = half ? W1 : W;
        const void* Asrc = half ? A1v : Av;
        __syncthreads();
        for (int f = tid; f < 64 * (NO / 4); f += 256) {
            const int kp = f / (NO / 4);
            const int n4 = f % (NO / 4);
            const float4 a = *(const float4*)(Wsrc + (size_t)(2 * kp) * NO + n4 * 4);
            const float4 b = *(const float4*)(Wsrc + (size_t)(2 * kp + 1) * NO + n4 * 4);
            const int k = 2 * kp, kb = k >> 5, qq = (k >> 3) & 3, p = (k & 7) >> 1;
            const float av[4] = {a.x, a.y, a.z, a.w};
            const float bv[4] = {b.x, b.y, b.z, b.w};
#pragma unroll
            for (int j = 0; j < 4; j++) {
                int col = n4 * 4 + j;
                int c = col >> 4, nl = col & 15;
                unsigned pk = (unsigned)f2bf(av[j]) | ((unsigned)f2bf(bv[j]) << 16);
                ((unsigned*)Wp)[(((kb * CT + c) * 64) + qq * 16 + nl) * 4 + p] = pk;
            }
        }
        __syncthreads();
#pragma unroll
        for (int kb = 0; kb < 4; kb++) {
            short8 afr;
            if (AFP32) {
                const float* Af = (const float*)Asrc + (size_t)prow * 128 + kb * 32 + q * 8;
#pragma unroll
                for (int j = 0; j < 8; j++) afr[j] = (short)f2bf(Af[j]);
            } else {
                // channel-blocked bf16: slice kb, row arow, ch q*8..q*8+7
                afr = *(const short8*)((const unsigned short*)Asrc +
                                       ((size_t)kb * n + arow) * 32 + q * 8);
            }
#pragma unroll
            for (int c = 0; c < CT; c++) {
                short8 bfr = *(const short8*)(Wp + ((size_t)(kb * CT + c) * 64 + lane) * 8);
                acc[c] = __builtin_amdgcn_mfma_f32_16x16x32_bf16(afr, bfr, acc[c], 0, 0, 0);
            }
        }
    }

    if (DOTS) {
        float ps[4] = {0.f, 0.f, 0.f, 0.f}, pd[4] = {0.f, 0.f, 0.f, 0.f};
#pragma unroll
        for (int c = 0; c < CT; c++) {
            float sv = a_s[c * 16 + ml], dv = a_d[c * 16 + ml];
#pragma unroll
            for (int r = 0; r < 4; r++) {
                ps[r] = fmaf(acc[c][r], sv, ps[r]);
                pd[r] = fmaf(acc[c][r], dv, pd[r]);
            }
        }
#pragma unroll
        for (int off = 1; off < 16; off <<= 1) {
#pragma unroll
            for (int r = 0; r < 4; r++) {
                ps[r] += __shfl_xor(ps[r], off, 64);
                pd[r] += __shfl_xor(pd[r], off, 64);
            }
        }
        if (ml == 0) {
#pragma unroll
            for (int r = 0; r < 4; r++) {
                int row = row0 + q * 4 + r;
                if (row < n) { as_[row] = ps[r]; ad_[row] = pd[r]; }
            }
        }
    }

    float sc[4];
    if (SCALE) {
#pragma unroll
        for (int r = 0; r < 4; r++) {
            int row = row0 + q * 4 + r;
            sc[r] = scale[row < n ? row : 0];
        }
    }
#pragma unroll
    for (int c = 0; c < CT; c++) {
        float bv = BIASRELU ? bias[c * 16 + ml] : 0.0f;
        const int col = c * 16 + ml;
#pragma unroll
        for (int r = 0; r < 4; r++) {
            int row = row0 + q * 4 + r;
            if (row < n) {
                float v = acc[c][r];
                if (SCALE) v *= sc[r];
                if (BIASRELU) v = fmaxf(v + bv, 0.0f);
                C16[((size_t)(col >> 5) * n + row) * 32 + (col & 31)] = f2bf(v);
            }
        }
    }
}

// ---------------- CSR build: padded buckets (no pre-histogram) ----------------
__global__ __launch_bounds__(512) void binit_k(int* __restrict__ bcur,
                                               int* __restrict__ ghist, int nb) {
    int t = threadIdx.x;
    if (t < nb) bcur[t] = t * CAP;
    if (t < DMAX) ghist[t] = 0;
}

#define PART_CH 4096
__global__ __launch_bounds__(256) void part_k(
    const int* __restrict__ src, const int* __restrict__ dst,
    int* __restrict__ bcur, unsigned long long* __restrict__ part, int nE)
{
    __shared__ int cnt[NBMAX];
    __shared__ int cur[NBMAX];
    const int base = blockIdx.x * PART_CH;
    const int t = threadIdx.x;
    cnt[t] = 0;
    __syncthreads();
    int d[PART_CH / 256], s[PART_CH / 256];
#pragma unroll
    for (int j = 0; j < PART_CH / 256; j++) {
        int e = base + j * 256 + t;
        if (e < nE) {
            d[j] = dst[e]; s[j] = src[e];
            atomicAdd(&cnt[d[j] >> BUCKET_BITS], 1);
        } else d[j] = -1;
    }
    __syncthreads();
    {
        int c = cnt[t];
        cur[t] = c ? atomicAdd(&bcur[t], c) : 0;
    }
    __syncthreads();
#pragma unroll
    for (int j = 0; j < PART_CH / 256; j++) {
        if (d[j] >= 0) {
            int p = atomicAdd(&cur[d[j] >> BUCKET_BITS], 1);
            part[p] = ((unsigned long long)(unsigned)d[j] << 32) | (unsigned)s[j];
        }
    }
}

// scan bucket counts (bcur[b]-b*CAP) -> bofs (CSR bucket bases)
__global__ __launch_bounds__(256) void bscan_k(const int* __restrict__ bcur,
                                               int* __restrict__ bofs, int nb) {
    __shared__ int sm[256];
    const int t = threadIdx.x;
    int v = (t < nb) ? (bcur[t] - t * CAP) : 0;
    sm[t] = v;
    __syncthreads();
    for (int off = 1; off < 256; off <<= 1) {
        int tv = (t >= off) ? sm[t - off] : 0;
        __syncthreads();
        sm[t] += tv;
        __syncthreads();
    }
    if (t < nb) {
        bofs[t] = sm[t] - v;
        if (t == nb - 1) bofs[nb] = sm[t];
    }
}

__global__ __launch_bounds__(256) void csr_k(
    const unsigned long long* __restrict__ part, const int* __restrict__ bcur,
    const int* __restrict__ bofs, int* __restrict__ rowptr, int* __restrict__ srcs,
    float* __restrict__ dinv, float* __restrict__ invm,
    int* __restrict__ deg, int* __restrict__ ghist, int n, int nE)
{
    __shared__ int lcnt[BUCKET_SZ];
    __shared__ int sm[BUCKET_SZ];
    __shared__ int lcur[BUCKET_SZ];
    const int b = blockIdx.x;
    const int t = threadIdx.x;
    const int base_in = b * CAP;
    const int cntE = bcur[b] - base_in;
    const int base_out = bofs[b];

    lcnt[t] = 0;
    __syncthreads();
#pragma unroll 4
    for (int e = t; e < cntE; e += 256) {
        int dl = (int)(part[base_in + e] >> 32) & (BUCKET_SZ - 1);
        atomicAdd(&lcnt[dl], 1);
    }
    __syncthreads();
    int v = lcnt[t];
    sm[t] = v;
    __syncthreads();
    for (int off = 1; off < 256; off <<= 1) {
        int tv = (t >= off) ? sm[t - off] : 0;
        __syncthreads();
        sm[t] += tv;
        __syncthreads();
    }
    const int excl = sm[t] - v;
    const int node = (b << BUCKET_BITS) + t;
    if (node < n) {
        rowptr[node] = base_out + excl;
        float dg = (float)v;
        dinv[node] = rsqrtf(dg + 1.0f);
        invm[node] = 1.0f / fmaxf(dg, 1.0f);
        deg[node] = v;
        atomicAdd(&ghist[v < DMAX ? v : DMAX - 1], 1);
        if (node == n - 1) rowptr[n] = nE;
    }
    lcur[t] = excl;
    __syncthreads();
#pragma unroll 4
    for (int e = t; e < cntE; e += 256) {
        unsigned long long w = part[base_in + e];
        int dl = (int)(w >> 32) & (BUCKET_SZ - 1);
        int pos = atomicAdd(&lcur[dl], 1);
        srcs[base_out + pos] = (int)(unsigned)w;
    }
}

// ---------------- degree counting sort: scan, rank/perm, repack ----------------
__global__ __launch_bounds__(512) void dscan_k(
    const int* __restrict__ ghist, int* __restrict__ dbase,
    int* __restrict__ ebase, int* __restrict__ dcur)
{
    __shared__ int sa[DMAX], sb[DMAX];
    const int t = threadIdx.x;
    const int c = ghist[t];
    sa[t] = c; sb[t] = c * t;
    __syncthreads();
    for (int off = 1; off < DMAX; off <<= 1) {
        int va = (t >= off) ? sa[t - off] : 0;
        int vb = (t >= off) ? sb[t - off] : 0;
        __syncthreads();
        sa[t] += va; sb[t] += vb;
        __syncthreads();
    }
    dbase[t] = sa[t] - c;
    ebase[t] = sb[t] - c * t;
    dcur[t]  = sa[t] - c;
}

__global__ __launch_bounds__(256) void drank_k(
    const int* __restrict__ deg, int* __restrict__ dcur,
    const int* __restrict__ dbase, const int* __restrict__ ebase,
    int* __restrict__ rank, int* __restrict__ perm, int* __restrict__ rowptrS,
    const float* __restrict__ dinv, const float* __restrict__ invm,
    float* __restrict__ dinvS, float* __restrict__ invmS, int n, int nE)
{
    const int node = blockIdx.x * 256 + threadIdx.x;
    if (node >= n) return;
    const int d = deg[node];
    const int r = atomicAdd(&dcur[d], 1);
    rank[node] = r;
    perm[r] = node;
    rowptrS[r] = ebase[d] + (r - dbase[d]) * d;
    dinvS[r] = dinv[node];
    invmS[r] = invm[node];
    if (node == 0) rowptrS[n] = nE;
}

__global__ __launch_bounds__(256) void repack_k(
    const int* __restrict__ rank, const int* __restrict__ rowptr,
    const int* __restrict__ deg, const int* __restrict__ rowptrS,
    const int* __restrict__ srcs, int* __restrict__ srcsS, int n)
{
    const int node = blockIdx.x * 256 + threadIdx.x;
    if (node >= n) return;
    const int r = rank[node];
    const int ob = rowptr[node];
    const int d = deg[node];
    const int nb2 = rowptrS[r];
    for (int j = 0; j < d; j++)
        srcsS[nb2 + j] = rank[srcs[ob + j]];
}

// ---------------- GAT edge-weight precompute (rank-indexed, sorted CSR) -------
__global__ __launch_bounds__(256) void gatw_k(
    const int* __restrict__ rowptr, const int* __restrict__ srcs,
    const float* __restrict__ as_, const float* __restrict__ ad_,
    float* __restrict__ ew, float* __restrict__ rdn_, float* __restrict__ sw_, int n)
{
    const int node = blockIdx.x * 32 + (threadIdx.x >> 3);
    const int lane = threadIdx.x & 7;
    if (node >= n) return;
    const int beg = rowptr[node], end = rowptr[node + 1];
    const float ad_d = ad_[node];
    float psum = 0.f;
    for (int k = beg + lane; k < end; k += 8) {
        float e = __expf(leaky02(as_[srcs[k]] + ad_d));
        ew[k] = e;
        psum += e;
    }
#pragma unroll
    for (int off = 4; off > 0; off >>= 1) psum += __shfl_xor(psum, off, 64);
    if (lane == 0) {
        float se = __expf(leaky02(as_[node] + ad_d));
        float r = 1.0f / (psum + se);
        rdn_[node] = r;
        sw_[node] = se * r;
    }
}

// ---------------- bf16 gather v16: rank-indexed, degree-uniform waves ----------
// H channel-blocked [NCB][n][32], rank-indexed. Block = (cb, rank-group of 64);
// cb pinned to XCDs via blockIdx%8. 4 lanes per node, u32x4 per lane per edge.
// srcs/ew direct reads: sorted CSR => lockstep contiguous windows (L1-hot).
// MODE 0: SAGE mean; 1: GCN relu; 2: GAT (precomputed ew/rden/sw); 3: GCN out
// (fp32, scattered to original node via perm).
template<int MODE>
__device__ __forceinline__ void edge8(
    const char* __restrict__ Hb, unsigned loff,
    const int4a ia, const int4a ib,
    const float4a wa, const float4a wb,
    f32x2* acc)
{
    const int s[8] = {ia.x, ia.y, ia.z, ia.w, ib.x, ib.y, ib.z, ib.w};
    u32x4 h[8];
#pragma unroll
    for (int j = 0; j < 8; j++)
        h[j] = *(const u32x4*)(Hb + (size_t)(((unsigned)s[j] << 6) + loff));
    const float wv[8] = {wa.x, wa.y, wa.z, wa.w, wb.x, wb.y, wb.z, wb.w};
#pragma unroll
    for (int j = 0; j < 8; j++) {
        f32x2 w2 = {wv[j], wv[j]};
#pragma unroll
        for (int c = 0; c < 4; c++) {
            f32x2 hv = {bflo(h[j][c]), bfhi(h[j][c])};
            if (MODE == 2) acc[c] = w2 * hv + acc[c];   // v_pk_fma_f32
            else           acc[c] = acc[c] + hv;        // v_pk_add_f32
        }
    }
}

template<int NCB, int MODE>
__global__ __launch_bounds__(256) void gatherbf_k(
    const unsigned short* __restrict__ H16, float* __restrict__ outf,
    unsigned short* __restrict__ out16,
    const int* __restrict__ rowptr, const int* __restrict__ srcs,
    const float* __restrict__ scl,   // MODE0: invmS; MODE1/3: dinvS; MODE2: rdn_
    const float* __restrict__ sw_,   // MODE2: self-alpha
    const float* __restrict__ ew,    // MODE2: per-edge exp weights
    const float* __restrict__ bias,
    const int* __restrict__ permp,   // MODE3: rank -> original node
    int n)
{
    constexpr int XPC = 8 / NCB;     // XCDs per channel-slice
    constexpr int NPB = 64;          // nodes (ranks) per block

    const int bid = (int)blockIdx.x;
    const int xj = bid & 7;
    const int cb = xj / XPC;
    const int NG = (n + NPB - 1) / NPB;
    const int ng = (bid >> 3) * XPC + (xj % XPC);
    if (ng >= NG) return;

    const int tid = (int)threadIdx.x;
    const int node = ng * NPB + (tid >> 2);   // rank
    if (node >= n) return;
    const int lane = tid & 3;
    const int beg = rowptr[node], end = rowptr[node + 1];
    const char* __restrict__ Hb = (const char*)H16 + (size_t)cb * n * 64;
    const unsigned loff = (unsigned)lane * 16u;

    f32x2 acc[4];
#pragma unroll
    for (int c = 0; c < 4; c++) acc[c] = {0.f, 0.f};
    const float4a wdum = {0.f, 0.f, 0.f, 0.f};

    int k = beg;
    for (; k + 16 <= end; k += 16) {
        int4a ia0 = *(const int4a*)(srcs + k);
        int4a ib0 = *(const int4a*)(srcs + k + 4);
        int4a ia1 = *(const int4a*)(srcs + k + 8);
        int4a ib1 = *(const int4a*)(srcs + k + 12);
        float4a wa0 = wdum, wb0 = wdum, wa1 = wdum, wb1 = wdum;
        if (MODE == 2) {
            wa0 = *(const float4a*)(ew + k);      wb0 = *(const float4a*)(ew + k + 4);
            wa1 = *(const float4a*)(ew + k + 8);  wb1 = *(const float4a*)(ew + k + 12);
        }
        edge8<MODE>(Hb, loff, ia0, ib0, wa0, wb0, acc);
        edge8<MODE>(Hb, loff, ia1, ib1, wa1, wb1, acc);
    }
    for (; k + 8 <= end; k += 8) {
        int4a ia = *(const int4a*)(srcs + k);
        int4a ib = *(const int4a*)(srcs + k + 4);
        float4a wa = wdum, wb = wdum;
        if (MODE == 2) {
            wa = *(const float4a*)(ew + k);  wb = *(const float4a*)(ew + k + 4);
        }
        edge8<MODE>(Hb, loff, ia, ib, wa, wb, acc);
    }
    if (k < end) {
        // masked tail: over-reads stay inside workspace; idx clamped, w zeroed
        int4a ia = *(const int4a*)(srcs + k);
        int4a ib = *(const int4a*)(srcs + k + 4);
        int s[8] = {ia.x, ia.y, ia.z, ia.w, ib.x, ib.y, ib.z, ib.w};
        float wv[8];
        if (MODE == 2) {
            float4a wa = *(const float4a*)(ew + k);
            float4a wb = *(const float4a*)(ew + k + 4);
            wv[0] = wa.x; wv[1] = wa.y; wv[2] = wa.z; wv[3] = wa.w;
            wv[4] = wb.x; wv[5] = wb.y; wv[6] = wb.z; wv[7] = wb.w;
        }
#pragma unroll
        for (int j = 0; j < 8; j++) {
            bool act = (k + j) < end;
            s[j] = act ? s[j] : 0;
            if (MODE == 2) wv[j] = act ? wv[j] : 0.0f;
            else           wv[j] = act ? 1.0f : 0.0f;
        }
        u32x4 h[8];
#pragma unroll
        for (int j = 0; j < 8; j++)
            h[j] = *(const u32x4*)(Hb + (size_t)(((unsigned)s[j] << 6) + loff));
#pragma unroll
        for (int j = 0; j < 8; j++) {
            f32x2 w2 = {wv[j], wv[j]};
#pragma unroll
            for (int c = 0; c < 4; c++) {
                f32x2 hv = {bflo(h[j][c]), bfhi(h[j][c])};
                acc[c] = w2 * hv + acc[c];
            }
        }
    }

    const size_t orow = ((size_t)cb * n + node) * 4 + lane;   // u16x8 units
    float r[8];
    if (MODE == 0) {
        float sc = scl[node];
#pragma unroll
        for (int c = 0; c < 4; c++) { r[2*c] = acc[c].x * sc; r[2*c+1] = acc[c].y * sc; }
    } else {
        u32x4 su = *(const u32x4*)(Hb + (size_t)(((unsigned)node << 6) + loff));
        float sv[8];
#pragma unroll
        for (int c = 0; c < 4; c++) { sv[2*c] = bflo(su[c]); sv[2*c+1] = bfhi(su[c]); }
        const float4* b4 = (const float4*)bias;
        float4 ba = b4[cb * 8 + lane * 2], bb = b4[cb * 8 + lane * 2 + 1];
        float bv[8] = {ba.x, ba.y, ba.z, ba.w, bb.x, bb.y, bb.z, bb.w};
        float a8[8];
#pragma unroll
        for (int c = 0; c < 4; c++) { a8[2*c] = acc[c].x; a8[2*c+1] = acc[c].y; }
        if (MODE == 2) {
            float rden = scl[node], sw = sw_[node];
#pragma unroll
            for (int j = 0; j < 8; j++)
                r[j] = fmaxf(fmaf(rden, a8[j], fmaf(sw, sv[j], bv[j])), 0.f);
        } else {
            float dv = scl[node];
#pragma unroll
            for (int j = 0; j < 8; j++) {
                r[j] = dv * (a8[j] + sv[j]) + bv[j];
                if (MODE == 1) r[j] = fmaxf(r[j], 0.f);
            }
        }
    }
    if (MODE == 3) {
        const int pn = permp[node];
        float4* o4 = (float4*)(outf + (size_t)pn * 64 + cb * 32 + lane * 8);
        float4 ra = {r[0], r[1], r[2], r[3]}, rb = {r[4], r[5], r[6], r[7]};
        o4[0] = ra; o4[1] = rb;
    } else {
        u16x8 qv;
#pragma unroll
        for (int j = 0; j < 8; j++) qv[j] = f2bf(r[j]);
        ((u16x8*)out16)[orow] = qv;
    }
}

// ---------------------------------------------------------------------------
extern "C" void kernel_launch(void* const* d_in, const int* in_sizes, int n_in,
                              void* d_out, int out_size, void* d_ws, size_t ws_size,
                              hipStream_t stream)
{
    const float* x   = (const float*)d_in[0];
    const int*   ei  = (const int*)d_in[1];
    const float* W1  = (const float*)d_in[2];
    const float* b1  = (const float*)d_in[3];
    const float* Wl  = (const float*)d_in[4];
    const float* Wr  = (const float*)d_in[5];
    const float* bs  = (const float*)d_in[6];
    const float* Wg  = (const float*)d_in[7];
    const float* a_s = (const float*)d_in[8];
    const float* a_d = (const float*)d_in[9];
    const float* bg  = (const float*)d_in[10];
    const float* Wo  = (const float*)d_in[11];
    const float* bo  = (const float*)d_in[12];

    const int n  = in_sizes[0] / 128;
    const int nE = in_sizes[1] / 2;
    const int* src = ei;
    const int* dst = ei + nE;

    char* w = (char*)d_ws;
    auto alloc = [&](size_t bytes) { char* p = w; w += (bytes + 255) & ~(size_t)255; return p; };
    unsigned short* S0 = (unsigned short*)alloc((size_t)n * 128 * 2);
    unsigned short* S1 = (unsigned short*)alloc((size_t)n * 128 * 2);
    unsigned short* S2 = (unsigned short*)alloc((size_t)n * 128 * 2);
    const int nbv = (n + BUCKET_SZ - 1) / BUCKET_SZ;
    unsigned long long* part = (unsigned long long*)alloc((size_t)nbv * CAP * 8);
    int*   srcs   = (int*)alloc((size_t)nE * 4);
    int*   srcsS  = (int*)alloc((size_t)nE * 4);
    float* ew     = (float*)alloc((size_t)nE * 4);
    int*   rowptr = (int*)alloc((size_t)(n + 1) * 4);
    int*   rowptrS= (int*)alloc((size_t)(n + 1) * 4);
    int*   bofs   = (int*)alloc((NBMAX + 1) * 4);
    int*   bcur   = (int*)alloc(NBMAX * 4);
    float* dinv   = (float*)alloc((size_t)n * 4);
    float* invm   = (float*)alloc((size_t)n * 4);
    float* dinvS  = (float*)alloc((size_t)n * 4);
    float* invmS  = (float*)alloc((size_t)n * 4);
    float* as_    = (float*)alloc((size_t)n * 4);
    float* ad_    = (float*)alloc((size_t)n * 4);
    float* rdn_   = (float*)alloc((size_t)n * 4);
    float* sw_    = (float*)alloc((size_t)n * 4);
    int*   deg    = (int*)alloc((size_t)n * 4);
    int*   rank   = (int*)alloc((size_t)n * 4);
    int*   perm   = (int*)alloc((size_t)n * 4);
    int*   ghist  = (int*)alloc(DMAX * 4);
    int*   dbase  = (int*)alloc(DMAX * 4);
    int*   ebase  = (int*)alloc(DMAX * 4);
    int*   dcur   = (int*)alloc(DMAX * 4);

    const int TB = 256;
    auto cdiv = [](long long a, long long b) { return (int)((a + b - 1) / b); };
    const int nb     = nbv;
    const int gPart  = cdiv(nE, PART_CH);
    const int gGemm  = cdiv(n, 64);
    const int gNode  = cdiv(n, 256);
    const int NG     = cdiv(n, 64);            // rank-groups of 64
    const int gGa128 = 8 * cdiv(NG, 2);        // NCB=4, 2 XCDs per slice
    const int gGa64  = 8 * cdiv(NG, 4);        // NCB=2, 4 XCDs per slice
    const int gGatw  = cdiv(n, 32);

    // ---- CSR build + degree counting sort
    binit_k<<<1, 512, 0, stream>>>(bcur, ghist, nb);
    part_k<<<gPart, TB, 0, stream>>>(src, dst, bcur, part, nE);
    bscan_k<<<1, 256, 0, stream>>>(bcur, bofs, nb);
    csr_k<<<nb, TB, 0, stream>>>(part, bcur, bofs, rowptr, srcs, dinv, invm,
                                 deg, ghist, n, nE);
    dscan_k<<<1, DMAX, 0, stream>>>(ghist, dbase, ebase, dcur);
    drank_k<<<gNode, TB, 0, stream>>>(deg, dcur, dbase, ebase, rank, perm, rowptrS,
                                      dinv, invm, dinvS, invmS, n, nE);
    repack_k<<<gNode, TB, 0, stream>>>(rank, rowptr, deg, rowptrS, srcs, srcsS, n);

    // ---- Layer 1: GCN — x[perm]@W1 scaled by dinvS -> S0; gather -> S1 (=h1)
    mgemm_k<128, true, true, false, false, false, true><<<gGemm, TB, 0, stream>>>(
        x, W1, nullptr, nullptr, S0, dinvS, nullptr, nullptr, nullptr, nullptr, nullptr, perm, n);
    gatherbf_k<4, 1><<<gGa128, TB, 0, stream>>>(S0, nullptr, S1, rowptrS, srcsS,
                                                dinvS, nullptr, nullptr, b1, nullptr, n);

    // ---- Layer 2: SAGE — mean(S1) -> S0; dual GEMM mean@Wl + h1@Wr -> S2 (=h2)
    gatherbf_k<4, 0><<<gGa128, TB, 0, stream>>>(S1, nullptr, S0, rowptrS, srcsS,
                                                invmS, nullptr, nullptr, nullptr, nullptr, n);
    mgemm_k<128, false, false, true, true, false, false><<<gGemm, TB, 0, stream>>>(
        S0, Wl, S1, Wr, S2, nullptr, bs, nullptr, nullptr, nullptr, nullptr, nullptr, n);

    // ---- Layer 3: GAT — h2@Wg -> S1 (+fused dots); edge weights; gather -> S0
    mgemm_k<128, false, false, false, false, true, false><<<gGemm, TB, 0, stream>>>(
        S2, Wg, nullptr, nullptr, S1, nullptr, nullptr, a_s, a_d, as_, ad_, nullptr, n);
    gatw_k<<<gGatw, TB, 0, stream>>>(rowptrS, srcsS, as_, ad_, ew, rdn_, sw_, n);
    gatherbf_k<4, 2><<<gGa128, TB, 0, stream>>>(S1, nullptr, S0, rowptrS, srcsS,
                                                rdn_, sw_, ew, bg, nullptr, n);

    // ---- Output: h3@Wo scaled by dinvS -> S2; gather -> d_out (fp32, perm'd)
    mgemm_k<64, false, true, false, false, false, false><<<gGemm, TB, 0, stream>>>(
        S0, Wo, nullptr, nullptr, S2, dinvS, nullptr, nullptr, nullptr, nullptr, nullptr, nullptr, n);
    gatherbf_k<2, 3><<<gGa64, TB, 0, stream>>>(S2, (float*)d_out, nullptr, rowptrS, srcsS,
                                               dinvS, nullptr, nullptr, bo, perm, n);
}

// Round 5
// 509.783 us; speedup vs baseline: 1.1258x; 1.1258x over previous
//
#include <hip/hip_runtime.h>
#include <math.h>

// ---------------------------------------------------------------------------
// DynamicGNN: GCN -> SAGE(mean) -> GAT(1 head) -> GCN(128->64)
// N=50000, E=1.6M, D=128, OUT=64.
// v17: degree-sorted pipeline with direct-scatter CSR build. v16's sort
//      overhead (contended global atomics in csr_k/drank_k, serial repack_k)
//      replaced by: deghist (per-edge atomic deg), LDS-hier ghist + rank,
//      and escatter (edge -> sorted CSR in one pass). Bucket-CSR machinery
//      (binit/part/bscan/csr/repack) deleted. GEMMs/gathers = v16
//      (rank-indexed, channel-blocked [cb][N][32], XCD slice pinning).
//      14 dispatches total.
// ---------------------------------------------------------------------------

#define DMAX 512     // degree histogram bins (Poisson(32): max ~70)

typedef short short8 __attribute__((ext_vector_type(8)));
typedef float f32x4 __attribute__((ext_vector_type(4)));
typedef float f32x2 __attribute__((ext_vector_type(2)));
typedef unsigned int u32x4 __attribute__((ext_vector_type(4)));
typedef unsigned short u16x8 __attribute__((ext_vector_type(8)));
typedef int int4a __attribute__((ext_vector_type(4), aligned(4)));
typedef float float4a __attribute__((ext_vector_type(4), aligned(4)));

__device__ __forceinline__ float leaky02(float x) { return x > 0.0f ? x : 0.2f * x; }
__device__ __forceinline__ float bflo(unsigned u) { return __uint_as_float(u << 16); }
__device__ __forceinline__ float bfhi(unsigned u) { return __uint_as_float(u & 0xFFFF0000u); }
__device__ __forceinline__ unsigned short f2bf(float f) {
    unsigned u = __float_as_uint(f);
    u += 0x7FFFu + ((u >> 16) & 1u);   // round-to-nearest-even
    return (unsigned short)(u >> 16);
}

// ---------------- MFMA GEMM: C16 = bf16( scale? * (A@W (+A1@W1)) + bias )
// 256 thr = 4 waves; block = 64 rows; wave = 16 rows x NO cols.
// bf16 A tensors are channel-blocked [kb][n][32] (rank-indexed); fp32 A
// (layer 1) is node-major, read via perm when PERM. C16 written blocked.
template<int NO, bool AFP32, bool SCALE, bool BIASRELU, bool DUAL, bool DOTS, bool PERM>
__global__ __launch_bounds__(256) void mgemm_k(
    const void* __restrict__ Av, const float* __restrict__ W,
    const void* __restrict__ A1v, const float* __restrict__ W1,
    unsigned short* __restrict__ C16,
    const float* __restrict__ scale, const float* __restrict__ bias,
    const float* __restrict__ a_s, const float* __restrict__ a_d,
    float* __restrict__ as_, float* __restrict__ ad_,
    const int* __restrict__ permp, int n)
{
    constexpr int CT = NO / 16;
    __shared__ unsigned short Wp[128 * NO];   // packed B-frags (32/16 KB)
    const int tid = threadIdx.x;
    const int wave = tid >> 6, lane = tid & 63;
    const int q = lane >> 4, ml = lane & 15;
    const int row0 = blockIdx.x * 64 + wave * 16;
    int arow = row0 + ml; if (arow >= n) arow = n - 1;
    const int prow = (AFP32 && PERM) ? permp[arow] : arow;

    f32x4 acc[CT];
#pragma unroll
    for (int c = 0; c < CT; c++) acc[c] = {0.f, 0.f, 0.f, 0.f};

    for (int half = 0; half < (DUAL ? 2 : 1); half++) {
        const float* Wsrc = half ? W1 : W;
        const void* Asrc = half ? A1v : Av;
        __syncthreads();
        for (int f = tid; f < 64 * (NO / 4); f += 256) {
            const int kp = f / (NO / 4);
            const int n4 = f % (NO / 4);
            const float4 a = *(const float4*)(Wsrc + (size_t)(2 * kp) * NO + n4 * 4);
            const float4 b = *(const float4*)(Wsrc + (size_t)(2 * kp + 1) * NO + n4 * 4);
            const int k = 2 * kp, kb = k >> 5, qq = (k >> 3) & 3, p = (k & 7) >> 1;
            const float av[4] = {a.x, a.y, a.z, a.w};
            const float bv[4] = {b.x, b.y, b.z, b.w};
#pragma unroll
            for (int j = 0; j < 4; j++) {
                int col = n4 * 4 + j;
                int c = col >> 4, nl = col & 15;
                unsigned pk = (unsigned)f2bf(av[j]) | ((unsigned)f2bf(bv[j]) << 16);
                ((unsigned*)Wp)[(((kb * CT + c) * 64) + qq * 16 + nl) * 4 + p] = pk;
            }
        }
        __syncthreads();
#pragma unroll
        for (int kb = 0; kb < 4; kb++) {
            short8 afr;
            if (AFP32) {
                const float* Af = (const float*)Asrc + (size_t)prow * 128 + kb * 32 + q * 8;
#pragma unroll
                for (int j = 0; j < 8; j++) afr[j] = (short)f2bf(Af[j]);
            } else {
                // channel-blocked bf16: slice kb, row arow, ch q*8..q*8+7
                afr = *(const short8*)((const unsigned short*)Asrc +
                                       ((size_t)kb * n + arow) * 32 + q * 8);
            }
#pragma unroll
            for (int c = 0; c < CT; c++) {
                short8 bfr = *(const short8*)(Wp + ((size_t)(kb * CT + c) * 64 + lane) * 8);
                acc[c] = __builtin_amdgcn_mfma_f32_16x16x32_bf16(afr, bfr, acc[c], 0, 0, 0);
            }
        }
    }

    if (DOTS) {
        float ps[4] = {0.f, 0.f, 0.f, 0.f}, pd[4] = {0.f, 0.f, 0.f, 0.f};
#pragma unroll
        for (int c = 0; c < CT; c++) {
            float sv = a_s[c * 16 + ml], dv = a_d[c * 16 + ml];
#pragma unroll
            for (int r = 0; r < 4; r++) {
                ps[r] = fmaf(acc[c][r], sv, ps[r]);
                pd[r] = fmaf(acc[c][r], dv, pd[r]);
            }
        }
#pragma unroll
        for (int off = 1; off < 16; off <<= 1) {
#pragma unroll
            for (int r = 0; r < 4; r++) {
                ps[r] += __shfl_xor(ps[r], off, 64);
                pd[r] += __shfl_xor(pd[r], off, 64);
            }
        }
        if (ml == 0) {
#pragma unroll
            for (int r = 0; r < 4; r++) {
                int row = row0 + q * 4 + r;
                if (row < n) { as_[row] = ps[r]; ad_[row] = pd[r]; }
            }
        }
    }

    float sc[4];
    if (SCALE) {
#pragma unroll
        for (int r = 0; r < 4; r++) {
            int row = row0 + q * 4 + r;
            sc[r] = scale[row < n ? row : 0];
        }
    }
#pragma unroll
    for (int c = 0; c < CT; c++) {
        float bv = BIASRELU ? bias[c * 16 + ml] : 0.0f;
        const int col = c * 16 + ml;
#pragma unroll
        for (int r = 0; r < 4; r++) {
            int row = row0 + q * 4 + r;
            if (row < n) {
                float v = acc[c][r];
                if (SCALE) v *= sc[r];
                if (BIASRELU) v = fmaxf(v + bv, 0.0f);
                C16[((size_t)(col >> 5) * n + row) * 32 + (col & 31)] = f2bf(v);
            }
        }
    }
}

// ---------------- sorted-CSR build v17: direct scatter, no bucket pass -------
__global__ __launch_bounds__(256) void zinit_k(int* __restrict__ deg,
                                               int* __restrict__ ghist, int n) {
    const int i = blockIdx.x * 256 + threadIdx.x;
    if (i < n) deg[i] = 0;
    if (i < DMAX) ghist[i] = 0;
}

// per-edge degree count: 1.6M atomics over 50K addresses (~32-way) — parallel
__global__ __launch_bounds__(256) void deghist_k(
    const int* __restrict__ dst, int* __restrict__ deg, int nE)
{
    const int base = blockIdx.x * 1024 + threadIdx.x;
#pragma unroll
    for (int j = 0; j < 4; j++) {
        int e = base + j * 256;
        if (e < nE) atomicAdd(&deg[dst[e]], 1);
    }
}

// per-block LDS degree histogram -> low-contention global merge
__global__ __launch_bounds__(256) void ghist_k(
    const int* __restrict__ deg, int* __restrict__ ghist, int n)
{
    __shared__ int lh[DMAX];
    const int t = threadIdx.x;
    for (int i = t; i < DMAX; i += 256) lh[i] = 0;
    __syncthreads();
    const int node = blockIdx.x * 256 + t;
    if (node < n) {
        int d = deg[node];
        atomicAdd(&lh[d < DMAX ? d : DMAX - 1], 1);
    }
    __syncthreads();
    for (int i = t; i < DMAX; i += 256)
        if (lh[i]) atomicAdd(&ghist[i], lh[i]);
}

// scan degree hist: dbase (rank base per degree), ebase (edge base per degree)
__global__ __launch_bounds__(512) void dscan_k(
    const int* __restrict__ ghist, int* __restrict__ dbase,
    int* __restrict__ ebase, int* __restrict__ dcur)
{
    __shared__ int sa[DMAX], sb[DMAX];
    const int t = threadIdx.x;
    const int c = ghist[t];
    sa[t] = c; sb[t] = c * t;
    __syncthreads();
    for (int off = 1; off < DMAX; off <<= 1) {
        int va = (t >= off) ? sa[t - off] : 0;
        int vb = (t >= off) ? sb[t - off] : 0;
        __syncthreads();
        sa[t] += va; sb[t] += vb;
        __syncthreads();
    }
    dbase[t] = sa[t] - c;
    ebase[t] = sb[t] - c * t;
    dcur[t]  = sa[t] - c;
}

// LDS-hierarchical rank assignment: per-block hist -> 1 global atomic per
// (block,bin) -> intra-block offsets. Emits rank/perm/rowptrS/ecur/dinvS/invmS.
__global__ __launch_bounds__(256) void drank2_k(
    const int* __restrict__ deg, int* __restrict__ dcur,
    const int* __restrict__ dbase, const int* __restrict__ ebase,
    int* __restrict__ rank, int* __restrict__ perm, int* __restrict__ rowptrS,
    int* __restrict__ ecur, float* __restrict__ dinvS, float* __restrict__ invmS,
    int n, int nE)
{
    __shared__ int lh[DMAX], lbase[DMAX], lcur[DMAX];
    const int t = threadIdx.x;
    for (int i = t; i < DMAX; i += 256) { lh[i] = 0; lcur[i] = 0; }
    __syncthreads();
    const int node = blockIdx.x * 256 + t;
    int d = -1;
    if (node < n) {
        d = deg[node];
        if (d > DMAX - 1) d = DMAX - 1;
        atomicAdd(&lh[d], 1);
    }
    __syncthreads();
    for (int i = t; i < DMAX; i += 256) {
        int c = lh[i];
        lbase[i] = c ? atomicAdd(&dcur[i], c) : 0;
    }
    __syncthreads();
    if (node < n) {
        const int off = atomicAdd(&lcur[d], 1);
        const int r = lbase[d] + off;
        rank[node] = r;
        perm[r] = node;
        const int rp = ebase[d] + (r - dbase[d]) * d;
        rowptrS[r] = rp;
        ecur[r] = rp;
        dinvS[r] = rsqrtf((float)d + 1.0f);
        invmS[r] = 1.0f / fmaxf((float)d, 1.0f);
    }
    if (node == 0) rowptrS[n] = nE;
}

// per-edge scatter into sorted CSR: srcsS[pos] = rank[src], pos via ecur[rank[dst]]
__global__ __launch_bounds__(256) void escatter_k(
    const int* __restrict__ src, const int* __restrict__ dst,
    const int* __restrict__ rank, int* __restrict__ ecur,
    int* __restrict__ srcsS, int nE)
{
    const int base = blockIdx.x * 1024 + threadIdx.x;
#pragma unroll
    for (int j = 0; j < 4; j++) {
        int e = base + j * 256;
        if (e < nE) {
            int r = rank[dst[e]];
            int pos = atomicAdd(&ecur[r], 1);
            srcsS[pos] = rank[src[e]];
        }
    }
}

// ---------------- GAT edge-weight precompute (rank-indexed, sorted CSR) -------
__global__ __launch_bounds__(256) void gatw_k(
    const int* __restrict__ rowptr, const int* __restrict__ srcs,
    const float* __restrict__ as_, const float* __restrict__ ad_,
    float* __restrict__ ew, float* __restrict__ rdn_, float* __restrict__ sw_, int n)
{
    const int node = blockIdx.x * 32 + (threadIdx.x >> 3);
    const int lane = threadIdx.x & 7;
    if (node >= n) return;
    const int beg = rowptr[node], end = rowptr[node + 1];
    const float ad_d = ad_[node];
    float psum = 0.f;
    for (int k = beg + lane; k < end; k += 8) {
        float e = __expf(leaky02(as_[srcs[k]] + ad_d));
        ew[k] = e;
        psum += e;
    }
#pragma unroll
    for (int off = 4; off > 0; off >>= 1) psum += __shfl_xor(psum, off, 64);
    if (lane == 0) {
        float se = __expf(leaky02(as_[node] + ad_d));
        float r = 1.0f / (psum + se);
        rdn_[node] = r;
        sw_[node] = se * r;
    }
}

// ---------------- bf16 gather: rank-indexed, degree-uniform waves -------------
// H channel-blocked [NCB][n][32], rank-indexed. Block = (cb, rank-group of 64);
// cb pinned to XCDs via blockIdx%8. 4 lanes per node, u32x4 per lane per edge.
// srcs/ew direct reads: sorted CSR => lockstep contiguous windows (L1-hot).
// MODE 0: SAGE mean; 1: GCN relu; 2: GAT (precomputed ew/rden/sw); 3: GCN out
// (fp32, scattered to original node via perm).
template<int MODE>
__device__ __forceinline__ void edge8(
    const char* __restrict__ Hb, unsigned loff,
    const int4a ia, const int4a ib,
    const float4a wa, const float4a wb,
    f32x2* acc)
{
    const int s[8] = {ia.x, ia.y, ia.z, ia.w, ib.x, ib.y, ib.z, ib.w};
    u32x4 h[8];
#pragma unroll
    for (int j = 0; j < 8; j++)
        h[j] = *(const u32x4*)(Hb + (size_t)(((unsigned)s[j] << 6) + loff));
    const float wv[8] = {wa.x, wa.y, wa.z, wa.w, wb.x, wb.y, wb.z, wb.w};
#pragma unroll
    for (int j = 0; j < 8; j++) {
        f32x2 w2 = {wv[j], wv[j]};
#pragma unroll
        for (int c = 0; c < 4; c++) {
            f32x2 hv = {bflo(h[j][c]), bfhi(h[j][c])};
            if (MODE == 2) acc[c] = w2 * hv + acc[c];   // v_pk_fma_f32
            else           acc[c] = acc[c] + hv;        // v_pk_add_f32
        }
    }
}

template<int NCB, int MODE>
__global__ __launch_bounds__(256) void gatherbf_k(
    const unsigned short* __restrict__ H16, float* __restrict__ outf,
    unsigned short* __restrict__ out16,
    const int* __restrict__ rowptr, const int* __restrict__ srcs,
    const float* __restrict__ scl,   // MODE0: invmS; MODE1/3: dinvS; MODE2: rdn_
    const float* __restrict__ sw_,   // MODE2: self-alpha
    const float* __restrict__ ew,    // MODE2: per-edge exp weights
    const float* __restrict__ bias,
    const int* __restrict__ permp,   // MODE3: rank -> original node
    int n)
{
    constexpr int XPC = 8 / NCB;     // XCDs per channel-slice
    constexpr int NPB = 64;          // nodes (ranks) per block

    const int bid = (int)blockIdx.x;
    const int xj = bid & 7;
    const int cb = xj / XPC;
    const int NG = (n + NPB - 1) / NPB;
    const int ng = (bid >> 3) * XPC + (xj % XPC);
    if (ng >= NG) return;

    const int tid = (int)threadIdx.x;
    const int node = ng * NPB + (tid >> 2);   // rank
    if (node >= n) return;
    const int lane = tid & 3;
    const int beg = rowptr[node], end = rowptr[node + 1];
    const char* __restrict__ Hb = (const char*)H16 + (size_t)cb * n * 64;
    const unsigned loff = (unsigned)lane * 16u;

    f32x2 acc[4];
#pragma unroll
    for (int c = 0; c < 4; c++) acc[c] = {0.f, 0.f};
    const float4a wdum = {0.f, 0.f, 0.f, 0.f};

    int k = beg;
    for (; k + 16 <= end; k += 16) {
        int4a ia0 = *(const int4a*)(srcs + k);
        int4a ib0 = *(const int4a*)(srcs + k + 4);
        int4a ia1 = *(const int4a*)(srcs + k + 8);
        int4a ib1 = *(const int4a*)(srcs + k + 12);
        float4a wa0 = wdum, wb0 = wdum, wa1 = wdum, wb1 = wdum;
        if (MODE == 2) {
            wa0 = *(const float4a*)(ew + k);      wb0 = *(const float4a*)(ew + k + 4);
            wa1 = *(const float4a*)(ew + k + 8);  wb1 = *(const float4a*)(ew + k + 12);
        }
        edge8<MODE>(Hb, loff, ia0, ib0, wa0, wb0, acc);
        edge8<MODE>(Hb, loff, ia1, ib1, wa1, wb1, acc);
    }
    for (; k + 8 <= end; k += 8) {
        int4a ia = *(const int4a*)(srcs + k);
        int4a ib = *(const int4a*)(srcs + k + 4);
        float4a wa = wdum, wb = wdum;
        if (MODE == 2) {
            wa = *(const float4a*)(ew + k);  wb = *(const float4a*)(ew + k + 4);
        }
        edge8<MODE>(Hb, loff, ia, ib, wa, wb, acc);
    }
    if (k < end) {
        // masked tail: over-reads stay inside workspace; idx clamped, w zeroed
        int4a ia = *(const int4a*)(srcs + k);
        int4a ib = *(const int4a*)(srcs + k + 4);
        int s[8] = {ia.x, ia.y, ia.z, ia.w, ib.x, ib.y, ib.z, ib.w};
        float wv[8];
        if (MODE == 2) {
            float4a wa = *(const float4a*)(ew + k);
            float4a wb = *(const float4a*)(ew + k + 4);
            wv[0] = wa.x; wv[1] = wa.y; wv[2] = wa.z; wv[3] = wa.w;
            wv[4] = wb.x; wv[5] = wb.y; wv[6] = wb.z; wv[7] = wb.w;
        }
#pragma unroll
        for (int j = 0; j < 8; j++) {
            bool act = (k + j) < end;
            s[j] = act ? s[j] : 0;
            if (MODE == 2) wv[j] = act ? wv[j] : 0.0f;
            else           wv[j] = act ? 1.0f : 0.0f;
        }
        u32x4 h[8];
#pragma unroll
        for (int j = 0; j < 8; j++)
            h[j] = *(const u32x4*)(Hb + (size_t)(((unsigned)s[j] << 6) + loff));
#pragma unroll
        for (int j = 0; j < 8; j++) {
            f32x2 w2 = {wv[j], wv[j]};
#pragma unroll
            for (int c = 0; c < 4; c++) {
                f32x2 hv = {bflo(h[j][c]), bfhi(h[j][c])};
                acc[c] = w2 * hv + acc[c];
            }
        }
    }

    const size_t orow = ((size_t)cb * n + node) * 4 + lane;   // u16x8 units
    float r[8];
    if (MODE == 0) {
        float sc = scl[node];
#pragma unroll
        for (int c = 0; c < 4; c++) { r[2*c] = acc[c].x * sc; r[2*c+1] = acc[c].y * sc; }
    } else {
        u32x4 su = *(const u32x4*)(Hb + (size_t)(((unsigned)node << 6) + loff));
        float sv[8];
#pragma unroll
        for (int c = 0; c < 4; c++) { sv[2*c] = bflo(su[c]); sv[2*c+1] = bfhi(su[c]); }
        const float4* b4 = (const float4*)bias;
        float4 ba = b4[cb * 8 + lane * 2], bb = b4[cb * 8 + lane * 2 + 1];
        float bv[8] = {ba.x, ba.y, ba.z, ba.w, bb.x, bb.y, bb.z, bb.w};
        float a8[8];
#pragma unroll
        for (int c = 0; c < 4; c++) { a8[2*c] = acc[c].x; a8[2*c+1] = acc[c].y; }
        if (MODE == 2) {
            float rden = scl[node], sw = sw_[node];
#pragma unroll
            for (int j = 0; j < 8; j++)
                r[j] = fmaxf(fmaf(rden, a8[j], fmaf(sw, sv[j], bv[j])), 0.f);
        } else {
            float dv = scl[node];
#pragma unroll
            for (int j = 0; j < 8; j++) {
                r[j] = dv * (a8[j] + sv[j]) + bv[j];
                if (MODE == 1) r[j] = fmaxf(r[j], 0.f);
            }
        }
    }
    if (MODE == 3) {
        const int pn = permp[node];
        float4* o4 = (float4*)(outf + (size_t)pn * 64 + cb * 32 + lane * 8);
        float4 ra = {r[0], r[1], r[2], r[3]}, rb = {r[4], r[5], r[6], r[7]};
        o4[0] = ra; o4[1] = rb;
    } else {
        u16x8 qv;
#pragma unroll
        for (int j = 0; j < 8; j++) qv[j] = f2bf(r[j]);
        ((u16x8*)out16)[orow] = qv;
    }
}

// ---------------------------------------------------------------------------
extern "C" void kernel_launch(void* const* d_in, const int* in_sizes, int n_in,
                              void* d_out, int out_size, void* d_ws, size_t ws_size,
                              hipStream_t stream)
{
    const float* x   = (const float*)d_in[0];
    const int*   ei  = (const int*)d_in[1];
    const float* W1  = (const float*)d_in[2];
    const float* b1  = (const float*)d_in[3];
    const float* Wl  = (const float*)d_in[4];
    const float* Wr  = (const float*)d_in[5];
    const float* bs  = (const float*)d_in[6];
    const float* Wg  = (const float*)d_in[7];
    const float* a_s = (const float*)d_in[8];
    const float* a_d = (const float*)d_in[9];
    const float* bg  = (const float*)d_in[10];
    const float* Wo  = (const float*)d_in[11];
    const float* bo  = (const float*)d_in[12];

    const int n  = in_sizes[0] / 128;
    const int nE = in_sizes[1] / 2;
    const int* src = ei;
    const int* dst = ei + nE;

    char* w = (char*)d_ws;
    auto alloc = [&](size_t bytes) { char* p = w; w += (bytes + 255) & ~(size_t)255; return p; };
    unsigned short* S0 = (unsigned short*)alloc((size_t)n * 128 * 2);
    unsigned short* S1 = (unsigned short*)alloc((size_t)n * 128 * 2);
    unsigned short* S2 = (unsigned short*)alloc((size_t)n * 128 * 2);
    int*   srcsS  = (int*)alloc((size_t)nE * 4);
    float* ew     = (float*)alloc((size_t)nE * 4);
    int*   rowptrS= (int*)alloc((size_t)(n + 1) * 4);
    float* dinvS  = (float*)alloc((size_t)n * 4);
    float* invmS  = (float*)alloc((size_t)n * 4);
    float* as_    = (float*)alloc((size_t)n * 4);
    float* ad_    = (float*)alloc((size_t)n * 4);
    float* rdn_   = (float*)alloc((size_t)n * 4);
    float* sw_    = (float*)alloc((size_t)n * 4);
    int*   deg    = (int*)alloc((size_t)n * 4);
    int*   rank   = (int*)alloc((size_t)n * 4);
    int*   perm   = (int*)alloc((size_t)n * 4);
    int*   ecur   = (int*)alloc((size_t)n * 4);
    int*   ghist  = (int*)alloc(DMAX * 4);
    int*   dbase  = (int*)alloc(DMAX * 4);
    int*   ebase  = (int*)alloc(DMAX * 4);
    int*   dcur   = (int*)alloc(DMAX * 4);

    const int TB = 256;
    auto cdiv = [](long long a, long long b) { return (int)((a + b - 1) / b); };
    const int gNode  = cdiv(n, 256);
    const int gEdge4 = cdiv(nE, 1024);
    const int gGemm  = cdiv(n, 64);
    const int NG     = cdiv(n, 64);            // rank-groups of 64
    const int gGa128 = 8 * cdiv(NG, 2);        // NCB=4, 2 XCDs per slice
    const int gGa64  = 8 * cdiv(NG, 4);        // NCB=2, 4 XCDs per slice
    const int gGatw  = cdiv(n, 32);

    // ---- sorted-CSR build: deg hist -> rank -> direct edge scatter
    zinit_k<<<gNode, TB, 0, stream>>>(deg, ghist, n);
    deghist_k<<<gEdge4, TB, 0, stream>>>(dst, deg, nE);
    ghist_k<<<gNode, TB, 0, stream>>>(deg, ghist, n);
    dscan_k<<<1, DMAX, 0, stream>>>(ghist, dbase, ebase, dcur);
    drank2_k<<<gNode, TB, 0, stream>>>(deg, dcur, dbase, ebase, rank, perm,
                                       rowptrS, ecur, dinvS, invmS, n, nE);
    escatter_k<<<gEdge4, TB, 0, stream>>>(src, dst, rank, ecur, srcsS, nE);

    // ---- Layer 1: GCN — x[perm]@W1 scaled by dinvS -> S0; gather -> S1 (=h1)
    mgemm_k<128, true, true, false, false, false, true><<<gGemm, TB, 0, stream>>>(
        x, W1, nullptr, nullptr, S0, dinvS, nullptr, nullptr, nullptr, nullptr, nullptr, perm, n);
    gatherbf_k<4, 1><<<gGa128, TB, 0, stream>>>(S0, nullptr, S1, rowptrS, srcsS,
                                                dinvS, nullptr, nullptr, b1, nullptr, n);

    // ---- Layer 2: SAGE — mean(S1) -> S0; dual GEMM mean@Wl + h1@Wr -> S2 (=h2)
    gatherbf_k<4, 0><<<gGa128, TB, 0, stream>>>(S1, nullptr, S0, rowptrS, srcsS,
                                                invmS, nullptr, nullptr, nullptr, nullptr, n);
    mgemm_k<128, false, false, true, true, false, false><<<gGemm, TB, 0, stream>>>(
        S0, Wl, S1, Wr, S2, nullptr, bs, nullptr, nullptr, nullptr, nullptr, nullptr, n);

    // ---- Layer 3: GAT — h2@Wg -> S1 (+fused dots); edge weights; gather -> S0
    mgemm_k<128, false, false, false, false, true, false><<<gGemm, TB, 0, stream>>>(
        S2, Wg, nullptr, nullptr, S1, nullptr, nullptr, a_s, a_d, as_, ad_, nullptr, n);
    gatw_k<<<gGatw, TB, 0, stream>>>(rowptrS, srcsS, as_, ad_, ew, rdn_, sw_, n);
    gatherbf_k<4, 2><<<gGa128, TB, 0, stream>>>(S1, nullptr, S0, rowptrS, srcsS,
                                                rdn_, sw_, ew, bg, nullptr, n);

    // ---- Output: h3@Wo scaled by dinvS -> S2; gather -> d_out (fp32, perm'd)
    mgemm_k<64, false, true, false, false, false, false><<<gGemm, TB, 0, stream>>>(
        S0, Wo, nullptr, nullptr, S2, dinvS, nullptr, nullptr, nullptr, nullptr, nullptr, nullptr, n);
    gatherbf_k<2, 3><<<gGa64, TB, 0, stream>>>(S2, (float*)d_out, nullptr, rowptrS, srcsS,
                                               dinvS, nullptr, nullptr, bo, perm, n);
}

// Round 6
// 395.850 us; speedup vs baseline: 1.4499x; 1.2878x over previous
//
#include <hip/hip_runtime.h>
#include <math.h>

// ---------------------------------------------------------------------------
// DynamicGNN: GCN -> SAGE(mean) -> GAT(1 head) -> GCN(128->64)
// N=50000, E=1.6M, D=128, OUT=64.
// v18: rank-indexed compute (v17) + atomic-cheap sort build. Per-edge global
//      atomics (v17 escatter/deghist, ~100us each: fabric-side RMW) replaced
//      by v14's padded-bucket CSR (LDS atomics) + per-block LDS degree hist
//      + LDS-hier rank + atomic-free 8-lane repack. GEMMs/gathers/gatw
//      byte-identical to v17. 15 dispatches total.
// ---------------------------------------------------------------------------

#define BUCKET_BITS 8
#define BUCKET_SZ   256
#define NBMAX       256
#define CAP         10240   // padded bucket capacity (~8163 +- 90 expected)
#define DMAX        512     // degree histogram bins (Poisson(32): max ~70)

typedef short short8 __attribute__((ext_vector_type(8)));
typedef float f32x4 __attribute__((ext_vector_type(4)));
typedef float f32x2 __attribute__((ext_vector_type(2)));
typedef unsigned int u32x4 __attribute__((ext_vector_type(4)));
typedef unsigned short u16x8 __attribute__((ext_vector_type(8)));
typedef int int4a __attribute__((ext_vector_type(4), aligned(4)));
typedef float float4a __attribute__((ext_vector_type(4), aligned(4)));

__device__ __forceinline__ float leaky02(float x) { return x > 0.0f ? x : 0.2f * x; }
__device__ __forceinline__ float bflo(unsigned u) { return __uint_as_float(u << 16); }
__device__ __forceinline__ float bfhi(unsigned u) { return __uint_as_float(u & 0xFFFF0000u); }
__device__ __forceinline__ unsigned short f2bf(float f) {
    unsigned u = __float_as_uint(f);
    u += 0x7FFFu + ((u >> 16) & 1u);   // round-to-nearest-even
    return (unsigned short)(u >> 16);
}

// ---------------- MFMA GEMM: C16 = bf16( scale? * (A@W (+A1@W1)) + bias )
// 256 thr = 4 waves; block = 64 rows; wave = 16 rows x NO cols.
// bf16 A tensors are channel-blocked [kb][n][32] (rank-indexed); fp32 A
// (layer 1) is node-major, read via perm when PERM. C16 written blocked.
template<int NO, bool AFP32, bool SCALE, bool BIASRELU, bool DUAL, bool DOTS, bool PERM>
__global__ __launch_bounds__(256) void mgemm_k(
    const void* __restrict__ Av, const float* __restrict__ W,
    const void* __restrict__ A1v, const float* __restrict__ W1,
    unsigned short* __restrict__ C16,
    const float* __restrict__ scale, const float* __restrict__ bias,
    const float* __restrict__ a_s, const float* __restrict__ a_d,
    float* __restrict__ as_, float* __restrict__ ad_,
    const int* __restrict__ permp, int n)
{
    constexpr int CT = NO / 16;
    __shared__ unsigned short Wp[128 * NO];   // packed B-frags (32/16 KB)
    const int tid = threadIdx.x;
    const int wave = tid >> 6, lane = tid & 63;
    const int q = lane >> 4, ml = lane & 15;
    const int row0 = blockIdx.x * 64 + wave * 16;
    int arow = row0 + ml; if (arow >= n) arow = n - 1;
    const int prow = (AFP32 && PERM) ? permp[arow] : arow;

    f32x4 acc[CT];
#pragma unroll
    for (int c = 0; c < CT; c++) acc[c] = {0.f, 0.f, 0.f, 0.f};

    for (int half = 0; half < (DUAL ? 2 : 1); half++) {
        const float* Wsrc = half ? W1 : W;
        const void* Asrc = half ? A1v : Av;
        __syncthreads();
        for (int f = tid; f < 64 * (NO / 4); f += 256) {
            const int kp = f / (NO / 4);
            const int n4 = f % (NO / 4);
            const float4 a = *(const float4*)(Wsrc + (size_t)(2 * kp) * NO + n4 * 4);
            const float4 b = *(const float4*)(Wsrc + (size_t)(2 * kp + 1) * NO + n4 * 4);
            const int k = 2 * kp, kb = k >> 5, qq = (k >> 3) & 3, p = (k & 7) >> 1;
            const float av[4] = {a.x, a.y, a.z, a.w};
            const float bv[4] = {b.x, b.y, b.z, b.w};
#pragma unroll
            for (int j = 0; j < 4; j++) {
                int col = n4 * 4 + j;
                int c = col >> 4, nl = col & 15;
                unsigned pk = (unsigned)f2bf(av[j]) | ((unsigned)f2bf(bv[j]) << 16);
                ((unsigned*)Wp)[(((kb * CT + c) * 64) + qq * 16 + nl) * 4 + p] = pk;
            }
        }
        __syncthreads();
#pragma unroll
        for (int kb = 0; kb < 4; kb++) {
            short8 afr;
            if (AFP32) {
                const float* Af = (const float*)Asrc + (size_t)prow * 128 + kb * 32 + q * 8;
#pragma unroll
                for (int j = 0; j < 8; j++) afr[j] = (short)f2bf(Af[j]);
            } else {
                // channel-blocked bf16: slice kb, row arow, ch q*8..q*8+7
                afr = *(const short8*)((const unsigned short*)Asrc +
                                       ((size_t)kb * n + arow) * 32 + q * 8);
            }
#pragma unroll
            for (int c = 0; c < CT; c++) {
                short8 bfr = *(const short8*)(Wp + ((size_t)(kb * CT + c) * 64 + lane) * 8);
                acc[c] = __builtin_amdgcn_mfma_f32_16x16x32_bf16(afr, bfr, acc[c], 0, 0, 0);
            }
        }
    }

    if (DOTS) {
        float ps[4] = {0.f, 0.f, 0.f, 0.f}, pd[4] = {0.f, 0.f, 0.f, 0.f};
#pragma unroll
        for (int c = 0; c < CT; c++) {
            float sv = a_s[c * 16 + ml], dv = a_d[c * 16 + ml];
#pragma unroll
            for (int r = 0; r < 4; r++) {
                ps[r] = fmaf(acc[c][r], sv, ps[r]);
                pd[r] = fmaf(acc[c][r], dv, pd[r]);
            }
        }
#pragma unroll
        for (int off = 1; off < 16; off <<= 1) {
#pragma unroll
            for (int r = 0; r < 4; r++) {
                ps[r] += __shfl_xor(ps[r], off, 64);
                pd[r] += __shfl_xor(pd[r], off, 64);
            }
        }
        if (ml == 0) {
#pragma unroll
            for (int r = 0; r < 4; r++) {
                int row = row0 + q * 4 + r;
                if (row < n) { as_[row] = ps[r]; ad_[row] = pd[r]; }
            }
        }
    }

    float sc[4];
    if (SCALE) {
#pragma unroll
        for (int r = 0; r < 4; r++) {
            int row = row0 + q * 4 + r;
            sc[r] = scale[row < n ? row : 0];
        }
    }
#pragma unroll
    for (int c = 0; c < CT; c++) {
        float bv = BIASRELU ? bias[c * 16 + ml] : 0.0f;
        const int col = c * 16 + ml;
#pragma unroll
        for (int r = 0; r < 4; r++) {
            int row = row0 + q * 4 + r;
            if (row < n) {
                float v = acc[c][r];
                if (SCALE) v *= sc[r];
                if (BIASRELU) v = fmaxf(v + bv, 0.0f);
                C16[((size_t)(col >> 5) * n + row) * 32 + (col & 31)] = f2bf(v);
            }
        }
    }
}

// ---------------- CSR build: padded buckets (LDS atomics only) ----------------
__global__ __launch_bounds__(512) void binit_k(int* __restrict__ bcur,
                                               int* __restrict__ ghist, int nb) {
    int t = threadIdx.x;
    if (t < nb) bcur[t] = t * CAP;
    if (t < DMAX) ghist[t] = 0;
}

#define PART_CH 4096
__global__ __launch_bounds__(256) void part_k(
    const int* __restrict__ src, const int* __restrict__ dst,
    int* __restrict__ bcur, unsigned long long* __restrict__ part, int nE)
{
    __shared__ int cnt[NBMAX];
    __shared__ int cur[NBMAX];
    const int base = blockIdx.x * PART_CH;
    const int t = threadIdx.x;
    cnt[t] = 0;
    __syncthreads();
    int d[PART_CH / 256], s[PART_CH / 256];
#pragma unroll
    for (int j = 0; j < PART_CH / 256; j++) {
        int e = base + j * 256 + t;
        if (e < nE) {
            d[j] = dst[e]; s[j] = src[e];
            atomicAdd(&cnt[d[j] >> BUCKET_BITS], 1);
        } else d[j] = -1;
    }
    __syncthreads();
    {
        int c = cnt[t];
        cur[t] = c ? atomicAdd(&bcur[t], c) : 0;
    }
    __syncthreads();
#pragma unroll
    for (int j = 0; j < PART_CH / 256; j++) {
        if (d[j] >= 0) {
            int p = atomicAdd(&cur[d[j] >> BUCKET_BITS], 1);
            part[p] = ((unsigned long long)(unsigned)d[j] << 32) | (unsigned)s[j];
        }
    }
}

// scan bucket counts (bcur[b]-b*CAP) -> bofs (CSR bucket bases)
__global__ __launch_bounds__(256) void bscan_k(const int* __restrict__ bcur,
                                               int* __restrict__ bofs, int nb) {
    __shared__ int sm[256];
    const int t = threadIdx.x;
    int v = (t < nb) ? (bcur[t] - t * CAP) : 0;
    sm[t] = v;
    __syncthreads();
    for (int off = 1; off < 256; off <<= 1) {
        int tv = (t >= off) ? sm[t - off] : 0;
        __syncthreads();
        sm[t] += tv;
        __syncthreads();
    }
    if (t < nb) {
        bofs[t] = sm[t] - v;
        if (t == nb - 1) bofs[nb] = sm[t];
    }
}

// per-bucket CSR finalize + deg write + per-block LDS degree histogram
__global__ __launch_bounds__(256) void csr2_k(
    const unsigned long long* __restrict__ part, const int* __restrict__ bcur,
    const int* __restrict__ bofs, int* __restrict__ rowptr, int* __restrict__ srcs,
    int* __restrict__ deg, int* __restrict__ ghist, int n, int nE)
{
    __shared__ int lcnt[BUCKET_SZ];
    __shared__ int sm[BUCKET_SZ];
    __shared__ int lcur[BUCKET_SZ];
    __shared__ int lh[DMAX];
    const int b = blockIdx.x;
    const int t = threadIdx.x;
    const int base_in = b * CAP;
    const int cntE = bcur[b] - base_in;
    const int base_out = bofs[b];

    lcnt[t] = 0;
    lh[t] = 0; lh[t + 256] = 0;
    __syncthreads();
#pragma unroll 4
    for (int e = t; e < cntE; e += 256) {
        int dl = (int)(part[base_in + e] >> 32) & (BUCKET_SZ - 1);
        atomicAdd(&lcnt[dl], 1);
    }
    __syncthreads();
    int v = lcnt[t];
    sm[t] = v;
    __syncthreads();
    for (int off = 1; off < 256; off <<= 1) {
        int tv = (t >= off) ? sm[t - off] : 0;
        __syncthreads();
        sm[t] += tv;
        __syncthreads();
    }
    const int excl = sm[t] - v;
    const int node = (b << BUCKET_BITS) + t;
    if (node < n) {
        rowptr[node] = base_out + excl;
        deg[node] = v;
        atomicAdd(&lh[v < DMAX ? v : DMAX - 1], 1);   // LDS hist
        if (node == n - 1) rowptr[n] = nE;
    }
    lcur[t] = excl;
    __syncthreads();
    // low-contention global hist merge (~#distinct-bins atomics per block)
    if (lh[t]) atomicAdd(&ghist[t], lh[t]);
    if (lh[t + 256]) atomicAdd(&ghist[t + 256], lh[t + 256]);
#pragma unroll 4
    for (int e = t; e < cntE; e += 256) {
        unsigned long long w = part[base_in + e];
        int dl = (int)(w >> 32) & (BUCKET_SZ - 1);
        int pos = atomicAdd(&lcur[dl], 1);
        srcs[base_out + pos] = (int)(unsigned)w;
    }
}

// scan degree hist: dbase (rank base per degree), ebase (edge base per degree)
__global__ __launch_bounds__(512) void dscan_k(
    const int* __restrict__ ghist, int* __restrict__ dbase,
    int* __restrict__ ebase, int* __restrict__ dcur)
{
    __shared__ int sa[DMAX], sb[DMAX];
    const int t = threadIdx.x;
    const int c = ghist[t];
    sa[t] = c; sb[t] = c * t;
    __syncthreads();
    for (int off = 1; off < DMAX; off <<= 1) {
        int va = (t >= off) ? sa[t - off] : 0;
        int vb = (t >= off) ? sb[t - off] : 0;
        __syncthreads();
        sa[t] += va; sb[t] += vb;
        __syncthreads();
    }
    dbase[t] = sa[t] - c;
    ebase[t] = sb[t] - c * t;
    dcur[t]  = sa[t] - c;
}

// LDS-hierarchical rank assignment: per-block hist -> 1 global atomic per
// (block,bin) -> intra-block offsets. Emits rank/perm/rowptrS/dinvS/invmS.
__global__ __launch_bounds__(256) void drank2_k(
    const int* __restrict__ deg, int* __restrict__ dcur,
    const int* __restrict__ dbase, const int* __restrict__ ebase,
    int* __restrict__ rank, int* __restrict__ perm, int* __restrict__ rowptrS,
    float* __restrict__ dinvS, float* __restrict__ invmS, int n, int nE)
{
    __shared__ int lh[DMAX], lbase[DMAX], lcur[DMAX];
    const int t = threadIdx.x;
    for (int i = t; i < DMAX; i += 256) { lh[i] = 0; lcur[i] = 0; }
    __syncthreads();
    const int node = blockIdx.x * 256 + t;
    int d = -1;
    if (node < n) {
        d = deg[node];
        if (d > DMAX - 1) d = DMAX - 1;
        atomicAdd(&lh[d], 1);
    }
    __syncthreads();
    for (int i = t; i < DMAX; i += 256) {
        int c = lh[i];
        lbase[i] = c ? atomicAdd(&dcur[i], c) : 0;
    }
    __syncthreads();
    if (node < n) {
        const int off = atomicAdd(&lcur[d], 1);
        const int r = lbase[d] + off;
        rank[node] = r;
        perm[r] = node;
        rowptrS[r] = ebase[d] + (r - dbase[d]) * d;
        dinvS[r] = rsqrtf((float)d + 1.0f);
        invmS[r] = 1.0f / fmaxf((float)d, 1.0f);
    }
    if (node == 0) rowptrS[n] = nE;
}

// atomic-free repack: 8 lanes/node copy bucket-CSR run -> sorted position,
// translating src ids through rank[] (L2-resident 200KB table).
__global__ __launch_bounds__(256) void repack8_k(
    const int* __restrict__ rank, const int* __restrict__ rowptr,
    const int* __restrict__ deg, const int* __restrict__ rowptrS,
    const int* __restrict__ srcs, int* __restrict__ srcsS, int n)
{
    const int node = blockIdx.x * 32 + (threadIdx.x >> 3);
    const int lane = threadIdx.x & 7;
    if (node >= n) return;
    const int r = rank[node];
    const int ob = rowptr[node];
    const int d = deg[node];
    const int nb2 = rowptrS[r];
    for (int j = lane; j < d; j += 8)
        srcsS[nb2 + j] = rank[srcs[ob + j]];
}

// ---------------- GAT edge-weight precompute (rank-indexed, sorted CSR) -------
__global__ __launch_bounds__(256) void gatw_k(
    const int* __restrict__ rowptr, const int* __restrict__ srcs,
    const float* __restrict__ as_, const float* __restrict__ ad_,
    float* __restrict__ ew, float* __restrict__ rdn_, float* __restrict__ sw_, int n)
{
    const int node = blockIdx.x * 32 + (threadIdx.x >> 3);
    const int lane = threadIdx.x & 7;
    if (node >= n) return;
    const int beg = rowptr[node], end = rowptr[node + 1];
    const float ad_d = ad_[node];
    float psum = 0.f;
    for (int k = beg + lane; k < end; k += 8) {
        float e = __expf(leaky02(as_[srcs[k]] + ad_d));
        ew[k] = e;
        psum += e;
    }
#pragma unroll
    for (int off = 4; off > 0; off >>= 1) psum += __shfl_xor(psum, off, 64);
    if (lane == 0) {
        float se = __expf(leaky02(as_[node] + ad_d));
        float r = 1.0f / (psum + se);
        rdn_[node] = r;
        sw_[node] = se * r;
    }
}

// ---------------- bf16 gather: rank-indexed, degree-uniform waves -------------
// H channel-blocked [NCB][n][32], rank-indexed. Block = (cb, rank-group of 64);
// cb pinned to XCDs via blockIdx%8. 4 lanes per node, u32x4 per lane per edge.
// srcs/ew direct reads: sorted CSR => lockstep contiguous windows (L1-hot).
// MODE 0: SAGE mean; 1: GCN relu; 2: GAT (precomputed ew/rden/sw); 3: GCN out
// (fp32, scattered to original node via perm).
template<int MODE>
__device__ __forceinline__ void edge8(
    const char* __restrict__ Hb, unsigned loff,
    const int4a ia, const int4a ib,
    const float4a wa, const float4a wb,
    f32x2* acc)
{
    const int s[8] = {ia.x, ia.y, ia.z, ia.w, ib.x, ib.y, ib.z, ib.w};
    u32x4 h[8];
#pragma unroll
    for (int j = 0; j < 8; j++)
        h[j] = *(const u32x4*)(Hb + (size_t)(((unsigned)s[j] << 6) + loff));
    const float wv[8] = {wa.x, wa.y, wa.z, wa.w, wb.x, wb.y, wb.z, wb.w};
#pragma unroll
    for (int j = 0; j < 8; j++) {
        f32x2 w2 = {wv[j], wv[j]};
#pragma unroll
        for (int c = 0; c < 4; c++) {
            f32x2 hv = {bflo(h[j][c]), bfhi(h[j][c])};
            if (MODE == 2) acc[c] = w2 * hv + acc[c];   // v_pk_fma_f32
            else           acc[c] = acc[c] + hv;        // v_pk_add_f32
        }
    }
}

template<int NCB, int MODE>
__global__ __launch_bounds__(256) void gatherbf_k(
    const unsigned short* __restrict__ H16, float* __restrict__ outf,
    unsigned short* __restrict__ out16,
    const int* __restrict__ rowptr, const int* __restrict__ srcs,
    const float* __restrict__ scl,   // MODE0: invmS; MODE1/3: dinvS; MODE2: rdn_
    const float* __restrict__ sw_,   // MODE2: self-alpha
    const float* __restrict__ ew,    // MODE2: per-edge exp weights
    const float* __restrict__ bias,
    const int* __restrict__ permp,   // MODE3: rank -> original node
    int n)
{
    constexpr int XPC = 8 / NCB;     // XCDs per channel-slice
    constexpr int NPB = 64;          // nodes (ranks) per block

    const int bid = (int)blockIdx.x;
    const int xj = bid & 7;
    const int cb = xj / XPC;
    const int NG = (n + NPB - 1) / NPB;
    const int ng = (bid >> 3) * XPC + (xj % XPC);
    if (ng >= NG) return;

    const int tid = (int)threadIdx.x;
    const int node = ng * NPB + (tid >> 2);   // rank
    if (node >= n) return;
    const int lane = tid & 3;
    const int beg = rowptr[node], end = rowptr[node + 1];
    const char* __restrict__ Hb = (const char*)H16 + (size_t)cb * n * 64;
    const unsigned loff = (unsigned)lane * 16u;

    f32x2 acc[4];
#pragma unroll
    for (int c = 0; c < 4; c++) acc[c] = {0.f, 0.f};
    const float4a wdum = {0.f, 0.f, 0.f, 0.f};

    int k = beg;
    for (; k + 16 <= end; k += 16) {
        int4a ia0 = *(const int4a*)(srcs + k);
        int4a ib0 = *(const int4a*)(srcs + k + 4);
        int4a ia1 = *(const int4a*)(srcs + k + 8);
        int4a ib1 = *(const int4a*)(srcs + k + 12);
        float4a wa0 = wdum, wb0 = wdum, wa1 = wdum, wb1 = wdum;
        if (MODE == 2) {
            wa0 = *(const float4a*)(ew + k);      wb0 = *(const float4a*)(ew + k + 4);
            wa1 = *(const float4a*)(ew + k + 8);  wb1 = *(const float4a*)(ew + k + 12);
        }
        edge8<MODE>(Hb, loff, ia0, ib0, wa0, wb0, acc);
        edge8<MODE>(Hb, loff, ia1, ib1, wa1, wb1, acc);
    }
    for (; k + 8 <= end; k += 8) {
        int4a ia = *(const int4a*)(srcs + k);
        int4a ib = *(const int4a*)(srcs + k + 4);
        float4a wa = wdum, wb = wdum;
        if (MODE == 2) {
            wa = *(const float4a*)(ew + k);  wb = *(const float4a*)(ew + k + 4);
        }
        edge8<MODE>(Hb, loff, ia, ib, wa, wb, acc);
    }
    if (k < end) {
        // masked tail: over-reads stay inside workspace; idx clamped, w zeroed
        int4a ia = *(const int4a*)(srcs + k);
        int4a ib = *(const int4a*)(srcs + k + 4);
        int s[8] = {ia.x, ia.y, ia.z, ia.w, ib.x, ib.y, ib.z, ib.w};
        float wv[8];
        if (MODE == 2) {
            float4a wa = *(const float4a*)(ew + k);
            float4a wb = *(const float4a*)(ew + k + 4);
            wv[0] = wa.x; wv[1] = wa.y; wv[2] = wa.z; wv[3] = wa.w;
            wv[4] = wb.x; wv[5] = wb.y; wv[6] = wb.z; wv[7] = wb.w;
        }
#pragma unroll
        for (int j = 0; j < 8; j++) {
            bool act = (k + j) < end;
            s[j] = act ? s[j] : 0;
            if (MODE == 2) wv[j] = act ? wv[j] : 0.0f;
            else           wv[j] = act ? 1.0f : 0.0f;
        }
        u32x4 h[8];
#pragma unroll
        for (int j = 0; j < 8; j++)
            h[j] = *(const u32x4*)(Hb + (size_t)(((unsigned)s[j] << 6) + loff));
#pragma unroll
        for (int j = 0; j < 8; j++) {
            f32x2 w2 = {wv[j], wv[j]};
#pragma unroll
            for (int c = 0; c < 4; c++) {
                f32x2 hv = {bflo(h[j][c]), bfhi(h[j][c])};
                acc[c] = w2 * hv + acc[c];
            }
        }
    }

    const size_t orow = ((size_t)cb * n + node) * 4 + lane;   // u16x8 units
    float r[8];
    if (MODE == 0) {
        float sc = scl[node];
#pragma unroll
        for (int c = 0; c < 4; c++) { r[2*c] = acc[c].x * sc; r[2*c+1] = acc[c].y * sc; }
    } else {
        u32x4 su = *(const u32x4*)(Hb + (size_t)(((unsigned)node << 6) + loff));
        float sv[8];
#pragma unroll
        for (int c = 0; c < 4; c++) { sv[2*c] = bflo(su[c]); sv[2*c+1] = bfhi(su[c]); }
        const float4* b4 = (const float4*)bias;
        float4 ba = b4[cb * 8 + lane * 2], bb = b4[cb * 8 + lane * 2 + 1];
        float bv[8] = {ba.x, ba.y, ba.z, ba.w, bb.x, bb.y, bb.z, bb.w};
        float a8[8];
#pragma unroll
        for (int c = 0; c < 4; c++) { a8[2*c] = acc[c].x; a8[2*c+1] = acc[c].y; }
        if (MODE == 2) {
            float rden = scl[node], sw = sw_[node];
#pragma unroll
            for (int j = 0; j < 8; j++)
                r[j] = fmaxf(fmaf(rden, a8[j], fmaf(sw, sv[j], bv[j])), 0.f);
        } else {
            float dv = scl[node];
#pragma unroll
            for (int j = 0; j < 8; j++) {
                r[j] = dv * (a8[j] + sv[j]) + bv[j];
                if (MODE == 1) r[j] = fmaxf(r[j], 0.f);
            }
        }
    }
    if (MODE == 3) {
        const int pn = permp[node];
        float4* o4 = (float4*)(outf + (size_t)pn * 64 + cb * 32 + lane * 8);
        float4 ra = {r[0], r[1], r[2], r[3]}, rb = {r[4], r[5], r[6], r[7]};
        o4[0] = ra; o4[1] = rb;
    } else {
        u16x8 qv;
#pragma unroll
        for (int j = 0; j < 8; j++) qv[j] = f2bf(r[j]);
        ((u16x8*)out16)[orow] = qv;
    }
}

// ---------------------------------------------------------------------------
extern "C" void kernel_launch(void* const* d_in, const int* in_sizes, int n_in,
                              void* d_out, int out_size, void* d_ws, size_t ws_size,
                              hipStream_t stream)
{
    const float* x   = (const float*)d_in[0];
    const int*   ei  = (const int*)d_in[1];
    const float* W1  = (const float*)d_in[2];
    const float* b1  = (const float*)d_in[3];
    const float* Wl  = (const float*)d_in[4];
    const float* Wr  = (const float*)d_in[5];
    const float* bs  = (const float*)d_in[6];
    const float* Wg  = (const float*)d_in[7];
    const float* a_s = (const float*)d_in[8];
    const float* a_d = (const float*)d_in[9];
    const float* bg  = (const float*)d_in[10];
    const float* Wo  = (const float*)d_in[11];
    const float* bo  = (const float*)d_in[12];

    const int n  = in_sizes[0] / 128;
    const int nE = in_sizes[1] / 2;
    const int* src = ei;
    const int* dst = ei + nE;

    char* w = (char*)d_ws;
    auto alloc = [&](size_t bytes) { char* p = w; w += (bytes + 255) & ~(size_t)255; return p; };
    unsigned short* S0 = (unsigned short*)alloc((size_t)n * 128 * 2);
    unsigned short* S1 = (unsigned short*)alloc((size_t)n * 128 * 2);
    unsigned short* S2 = (unsigned short*)alloc((size_t)n * 128 * 2);
    const int nbv = (n + BUCKET_SZ - 1) / BUCKET_SZ;
    unsigned long long* part = (unsigned long long*)alloc((size_t)nbv * CAP * 8);
    int*   srcs   = (int*)alloc((size_t)nE * 4);
    int*   srcsS  = (int*)alloc((size_t)nE * 4);
    float* ew     = (float*)alloc((size_t)nE * 4);
    int*   rowptr = (int*)alloc((size_t)(n + 1) * 4);
    int*   rowptrS= (int*)alloc((size_t)(n + 1) * 4);
    int*   bofs   = (int*)alloc((NBMAX + 1) * 4);
    int*   bcur   = (int*)alloc(NBMAX * 4);
    float* dinvS  = (float*)alloc((size_t)n * 4);
    float* invmS  = (float*)alloc((size_t)n * 4);
    float* as_    = (float*)alloc((size_t)n * 4);
    float* ad_    = (float*)alloc((size_t)n * 4);
    float* rdn_   = (float*)alloc((size_t)n * 4);
    float* sw_    = (float*)alloc((size_t)n * 4);
    int*   deg    = (int*)alloc((size_t)n * 4);
    int*   rank   = (int*)alloc((size_t)n * 4);
    int*   perm   = (int*)alloc((size_t)n * 4);
    int*   ghist  = (int*)alloc(DMAX * 4);
    int*   dbase  = (int*)alloc(DMAX * 4);
    int*   ebase  = (int*)alloc(DMAX * 4);
    int*   dcur   = (int*)alloc(DMAX * 4);

    const int TB = 256;
    auto cdiv = [](long long a, long long b) { return (int)((a + b - 1) / b); };
    const int nb     = nbv;
    const int gPart  = cdiv(nE, PART_CH);
    const int gNode  = cdiv(n, 256);
    const int gNode32= cdiv(n, 32);
    const int gGemm  = cdiv(n, 64);
    const int NG     = cdiv(n, 64);            // rank-groups of 64
    const int gGa128 = 8 * cdiv(NG, 2);        // NCB=4, 2 XCDs per slice
    const int gGa64  = 8 * cdiv(NG, 4);        // NCB=2, 4 XCDs per slice

    // ---- bucket CSR (LDS atomics) + degree sort (per-block-bin atomics)
    binit_k<<<1, 512, 0, stream>>>(bcur, ghist, nb);
    part_k<<<gPart, TB, 0, stream>>>(src, dst, bcur, part, nE);
    bscan_k<<<1, 256, 0, stream>>>(bcur, bofs, nb);
    csr2_k<<<nb, TB, 0, stream>>>(part, bcur, bofs, rowptr, srcs, deg, ghist, n, nE);
    dscan_k<<<1, DMAX, 0, stream>>>(ghist, dbase, ebase, dcur);
    drank2_k<<<gNode, TB, 0, stream>>>(deg, dcur, dbase, ebase, rank, perm,
                                       rowptrS, dinvS, invmS, n, nE);
    repack8_k<<<gNode32, TB, 0, stream>>>(rank, rowptr, deg, rowptrS, srcs, srcsS, n);

    // ---- Layer 1: GCN — x[perm]@W1 scaled by dinvS -> S0; gather -> S1 (=h1)
    mgemm_k<128, true, true, false, false, false, true><<<gGemm, TB, 0, stream>>>(
        x, W1, nullptr, nullptr, S0, dinvS, nullptr, nullptr, nullptr, nullptr, nullptr, perm, n);
    gatherbf_k<4, 1><<<gGa128, TB, 0, stream>>>(S0, nullptr, S1, rowptrS, srcsS,
                                                dinvS, nullptr, nullptr, b1, nullptr, n);

    // ---- Layer 2: SAGE — mean(S1) -> S0; dual GEMM mean@Wl + h1@Wr -> S2 (=h2)
    gatherbf_k<4, 0><<<gGa128, TB, 0, stream>>>(S1, nullptr, S0, rowptrS, srcsS,
                                                invmS, nullptr, nullptr, nullptr, nullptr, n);
    mgemm_k<128, false, false, true, true, false, false><<<gGemm, TB, 0, stream>>>(
        S0, Wl, S1, Wr, S2, nullptr, bs, nullptr, nullptr, nullptr, nullptr, nullptr, n);

    // ---- Layer 3: GAT — h2@Wg -> S1 (+fused dots); edge weights; gather -> S0
    mgemm_k<128, false, false, false, false, true, false><<<gGemm, TB, 0, stream>>>(
        S2, Wg, nullptr, nullptr, S1, nullptr, nullptr, a_s, a_d, as_, ad_, nullptr, n);
    gatw_k<<<gNode32, TB, 0, stream>>>(rowptrS, srcsS, as_, ad_, ew, rdn_, sw_, n);
    gatherbf_k<4, 2><<<gGa128, TB, 0, stream>>>(S1, nullptr, S0, rowptrS, srcsS,
                                                rdn_, sw_, ew, bg, nullptr, n);

    // ---- Output: h3@Wo scaled by dinvS -> S2; gather -> d_out (fp32, perm'd)
    mgemm_k<64, false, true, false, false, false, false><<<gGemm, TB, 0, stream>>>(
        S0, Wo, nullptr, nullptr, S2, dinvS, nullptr, nullptr, nullptr, nullptr, nullptr, nullptr, n);
    gatherbf_k<2, 3><<<gGa64, TB, 0, stream>>>(S2, (float*)d_out, nullptr, rowptrS, srcsS,
                                               dinvS, nullptr, nullptr, bo, perm, n);
}

// Round 7
// 351.197 us; speedup vs baseline: 1.6342x; 1.1271x over previous
//
#include <hip/hip_runtime.h>
#include <math.h>

// ---------------------------------------------------------------------------
// DynamicGNN: GCN -> SAGE(mean) -> GAT(1 head) -> GCN(128->64)
// N=50000, E=1.6M, D=128, OUT=64.
// v19: v14 gather (LDS-staged srcs/ew + XCD slice pinning, proven 46.6us/
//      FETCH 48MB) + v15 pk-f32x2 inner math; sort deleted (refuted: 51.7us,
//      FETCH 111MB). GEMMs de-staged: wpackall_k pre-packs all 5 weights into
//      MFMA fragment layout once; mgemm_k loads B-frags direct from global
//      (L2-hot), no LDS, no barriers. 13 dispatches total.
// ---------------------------------------------------------------------------

#define BUCKET_BITS 8
#define BUCKET_SZ   256
#define NBMAX       256
#define CAP         10240   // padded bucket capacity (~8163 +- 90 expected)
#define CAPE        2560    // staged edges per gather block (mean 2048 + 11 sigma)

typedef short short8 __attribute__((ext_vector_type(8)));
typedef float f32x4 __attribute__((ext_vector_type(4)));
typedef float f32x2 __attribute__((ext_vector_type(2)));
typedef unsigned int u32x4 __attribute__((ext_vector_type(4)));
typedef unsigned short u16x8 __attribute__((ext_vector_type(8)));

__device__ __forceinline__ float leaky02(float x) { return x > 0.0f ? x : 0.2f * x; }
__device__ __forceinline__ float bflo(unsigned u) { return __uint_as_float(u << 16); }
__device__ __forceinline__ float bfhi(unsigned u) { return __uint_as_float(u & 0xFFFF0000u); }
__device__ __forceinline__ unsigned short f2bf(float f) {
    unsigned u = __float_as_uint(f);
    u += 0x7FFFu + ((u >> 16) & 1u);   // round-to-nearest-even
    return (unsigned short)(u >> 16);
}

// ---------------- weight pre-pack: fp32 [128 x NO] -> MFMA B-frag u32 layout
// One dispatch, 5 blocks (W1, Wl, Wr, Wg: NO=128; Wo: NO=64). Replicates the
// old per-GEMM-block LDS pack exactly, done once into workspace.
__global__ __launch_bounds__(256) void wpackall_k(
    const float* __restrict__ W1, const float* __restrict__ Wl,
    const float* __restrict__ Wr, const float* __restrict__ Wg,
    const float* __restrict__ Wo,
    unsigned* __restrict__ P1, unsigned* __restrict__ Pl,
    unsigned* __restrict__ Pr, unsigned* __restrict__ Pg,
    unsigned* __restrict__ Po)
{
    const int b = blockIdx.x;
    const float* W; unsigned* P; int NO;
    if      (b == 0) { W = W1; P = P1; NO = 128; }
    else if (b == 1) { W = Wl; P = Pl; NO = 128; }
    else if (b == 2) { W = Wr; P = Pr; NO = 128; }
    else if (b == 3) { W = Wg; P = Pg; NO = 128; }
    else             { W = Wo; P = Po; NO = 64;  }
    const int CT = NO / 16;
    const int n4w = NO / 4;
    for (int f = threadIdx.x; f < 64 * n4w; f += 256) {
        const int kp = f / n4w;
        const int n4 = f % n4w;
        const float4 a = *(const float4*)(W + (size_t)(2 * kp) * NO + n4 * 4);
        const float4 bb = *(const float4*)(W + (size_t)(2 * kp + 1) * NO + n4 * 4);
        const int k = 2 * kp, kb = k >> 5, qq = (k >> 3) & 3, p = (k & 7) >> 1;
        const float av[4] = {a.x, a.y, a.z, a.w};
        const float bv[4] = {bb.x, bb.y, bb.z, bb.w};
#pragma unroll
        for (int j = 0; j < 4; j++) {
            int col = n4 * 4 + j;
            int c = col >> 4, nl = col & 15;
            unsigned pk = (unsigned)f2bf(av[j]) | ((unsigned)f2bf(bv[j]) << 16);
            P[(((kb * CT + c) * 64) + qq * 16 + nl) * 4 + p] = pk;
        }
    }
}

// ---------------- MFMA GEMM v19: B-frags direct from prepacked global -------
// 256 thr = 4 waves; block = 64 rows; wave = 16 rows x NO cols. No LDS, no
// barriers. bf16 A channel-blocked [kb][n][32]; fp32 A (layer 1) node-major.
// C16 written channel-blocked [col>>5][n][32].
template<int NO, bool AFP32, bool SCALE, bool BIASRELU, bool DUAL, bool DOTS>
__global__ __launch_bounds__(256) void mgemm_k(
    const void* __restrict__ Av, const unsigned short* __restrict__ Bp,
    const void* __restrict__ A1v, const unsigned short* __restrict__ Bp1,
    unsigned short* __restrict__ C16,
    const float* __restrict__ scale, const float* __restrict__ bias,
    const float* __restrict__ a_s, const float* __restrict__ a_d,
    float* __restrict__ as_, float* __restrict__ ad_, int n)
{
    constexpr int CT = NO / 16;
    const int tid = threadIdx.x;
    const int wave = tid >> 6, lane = tid & 63;
    const int q = lane >> 4, ml = lane & 15;
    const int row0 = blockIdx.x * 64 + wave * 16;
    int arow = row0 + ml; if (arow >= n) arow = n - 1;

    f32x4 acc[CT];
#pragma unroll
    for (int c = 0; c < CT; c++) acc[c] = {0.f, 0.f, 0.f, 0.f};

    for (int half = 0; half < (DUAL ? 2 : 1); half++) {
        const unsigned short* __restrict__ Bsrc = half ? Bp1 : Bp;
        const void* Asrc = half ? A1v : Av;
#pragma unroll
        for (int kb = 0; kb < 4; kb++) {
            short8 afr;
            if (AFP32) {
                const float* Af = (const float*)Asrc + (size_t)arow * 128 + kb * 32 + q * 8;
                float4 f0 = *(const float4*)Af;
                float4 f1 = *(const float4*)(Af + 4);
                afr[0] = (short)f2bf(f0.x); afr[1] = (short)f2bf(f0.y);
                afr[2] = (short)f2bf(f0.z); afr[3] = (short)f2bf(f0.w);
                afr[4] = (short)f2bf(f1.x); afr[5] = (short)f2bf(f1.y);
                afr[6] = (short)f2bf(f1.z); afr[7] = (short)f2bf(f1.w);
            } else {
                // channel-blocked bf16: slice kb, row arow, ch q*8..q*8+7
                afr = *(const short8*)((const unsigned short*)Asrc +
                                       ((size_t)kb * n + arow) * 32 + q * 8);
            }
            short8 bfr[CT];
#pragma unroll
            for (int c = 0; c < CT; c++)
                bfr[c] = *(const short8*)(Bsrc + ((size_t)(kb * CT + c) * 64 + lane) * 8);
#pragma unroll
            for (int c = 0; c < CT; c++)
                acc[c] = __builtin_amdgcn_mfma_f32_16x16x32_bf16(afr, bfr[c], acc[c], 0, 0, 0);
        }
    }

    if (DOTS) {
        float ps[4] = {0.f, 0.f, 0.f, 0.f}, pd[4] = {0.f, 0.f, 0.f, 0.f};
#pragma unroll
        for (int c = 0; c < CT; c++) {
            float sv = a_s[c * 16 + ml], dv = a_d[c * 16 + ml];
#pragma unroll
            for (int r = 0; r < 4; r++) {
                ps[r] = fmaf(acc[c][r], sv, ps[r]);
                pd[r] = fmaf(acc[c][r], dv, pd[r]);
            }
        }
#pragma unroll
        for (int off = 1; off < 16; off <<= 1) {
#pragma unroll
            for (int r = 0; r < 4; r++) {
                ps[r] += __shfl_xor(ps[r], off, 64);
                pd[r] += __shfl_xor(pd[r], off, 64);
            }
        }
        if (ml == 0) {
#pragma unroll
            for (int r = 0; r < 4; r++) {
                int row = row0 + q * 4 + r;
                if (row < n) { as_[row] = ps[r]; ad_[row] = pd[r]; }
            }
        }
    }

    float sc[4];
    if (SCALE) {
#pragma unroll
        for (int r = 0; r < 4; r++) {
            int row = row0 + q * 4 + r;
            sc[r] = scale[row < n ? row : 0];
        }
    }
#pragma unroll
    for (int c = 0; c < CT; c++) {
        float bv = BIASRELU ? bias[c * 16 + ml] : 0.0f;
        const int col = c * 16 + ml;
#pragma unroll
        for (int r = 0; r < 4; r++) {
            int row = row0 + q * 4 + r;
            if (row < n) {
                float v = acc[c][r];
                if (SCALE) v *= sc[r];
                if (BIASRELU) v = fmaxf(v + bv, 0.0f);
                C16[((size_t)(col >> 5) * n + row) * 32 + (col & 31)] = f2bf(v);
            }
        }
    }
}

// ---------------- CSR build: padded buckets (LDS atomics only) ----------------
__global__ void binit_k(int* __restrict__ bcur, int nb) {
    int t = threadIdx.x;
    if (t < nb) bcur[t] = t * CAP;
}

#define PART_CH 4096
__global__ __launch_bounds__(256) void part_k(
    const int* __restrict__ src, const int* __restrict__ dst,
    int* __restrict__ bcur, unsigned long long* __restrict__ part, int nE)
{
    __shared__ int cnt[NBMAX];
    __shared__ int cur[NBMAX];
    const int base = blockIdx.x * PART_CH;
    const int t = threadIdx.x;
    cnt[t] = 0;
    __syncthreads();
    int d[PART_CH / 256], s[PART_CH / 256];
#pragma unroll
    for (int j = 0; j < PART_CH / 256; j++) {
        int e = base + j * 256 + t;
        if (e < nE) {
            d[j] = dst[e]; s[j] = src[e];
            atomicAdd(&cnt[d[j] >> BUCKET_BITS], 1);
        } else d[j] = -1;
    }
    __syncthreads();
    {
        int c = cnt[t];
        cur[t] = c ? atomicAdd(&bcur[t], c) : 0;
    }
    __syncthreads();
#pragma unroll
    for (int j = 0; j < PART_CH / 256; j++) {
        if (d[j] >= 0) {
            int p = atomicAdd(&cur[d[j] >> BUCKET_BITS], 1);
            part[p] = ((unsigned long long)(unsigned)d[j] << 32) | (unsigned)s[j];
        }
    }
}

// scan bucket counts (bcur[b]-b*CAP) -> bofs (CSR bucket bases)
__global__ __launch_bounds__(256) void bscan_k(const int* __restrict__ bcur,
                                               int* __restrict__ bofs, int nb) {
    __shared__ int sm[256];
    const int t = threadIdx.x;
    int v = (t < nb) ? (bcur[t] - t * CAP) : 0;
    sm[t] = v;
    __syncthreads();
    for (int off = 1; off < 256; off <<= 1) {
        int tv = (t >= off) ? sm[t - off] : 0;
        __syncthreads();
        sm[t] += tv;
        __syncthreads();
    }
    if (t < nb) {
        bofs[t] = sm[t] - v;
        if (t == nb - 1) bofs[nb] = sm[t];
    }
}

__global__ __launch_bounds__(256) void csr_k(
    const unsigned long long* __restrict__ part, const int* __restrict__ bcur,
    const int* __restrict__ bofs, int* __restrict__ rowptr, int* __restrict__ srcs,
    float* __restrict__ dinv, float* __restrict__ invm, int n, int nE)
{
    __shared__ int lcnt[BUCKET_SZ];
    __shared__ int sm[BUCKET_SZ];
    __shared__ int lcur[BUCKET_SZ];
    const int b = blockIdx.x;
    const int t = threadIdx.x;
    const int base_in = b * CAP;
    const int cntE = bcur[b] - base_in;
    const int base_out = bofs[b];

    lcnt[t] = 0;
    __syncthreads();
#pragma unroll 4
    for (int e = t; e < cntE; e += 256) {
        int dl = (int)(part[base_in + e] >> 32) & (BUCKET_SZ - 1);
        atomicAdd(&lcnt[dl], 1);
    }
    __syncthreads();
    int v = lcnt[t];
    sm[t] = v;
    __syncthreads();
    for (int off = 1; off < 256; off <<= 1) {
        int tv = (t >= off) ? sm[t - off] : 0;
        __syncthreads();
        sm[t] += tv;
        __syncthreads();
    }
    const int excl = sm[t] - v;
    const int node = (b << BUCKET_BITS) + t;
    if (node < n) {
        rowptr[node] = base_out + excl;
        float dg = (float)v;
        dinv[node] = rsqrtf(dg + 1.0f);
        invm[node] = 1.0f / fmaxf(dg, 1.0f);
        if (node == n - 1) rowptr[n] = nE;
    }
    lcur[t] = excl;
    __syncthreads();
#pragma unroll 4
    for (int e = t; e < cntE; e += 256) {
        unsigned long long w = part[base_in + e];
        int dl = (int)(w >> 32) & (BUCKET_SZ - 1);
        int pos = atomicAdd(&lcur[dl], 1);
        srcs[base_out + pos] = (int)(unsigned)w;
    }
}

// ---------------- GAT edge-weight precompute: ew[e], rdn_[node], sw_[node] ----
__global__ __launch_bounds__(256) void gatw_k(
    const int* __restrict__ rowptr, const int* __restrict__ srcs,
    const float* __restrict__ as_, const float* __restrict__ ad_,
    float* __restrict__ ew, float* __restrict__ rdn_, float* __restrict__ sw_, int n)
{
    const int node = blockIdx.x * 32 + (threadIdx.x >> 3);
    const int lane = threadIdx.x & 7;
    if (node >= n) return;
    const int beg = rowptr[node], end = rowptr[node + 1];
    const float ad_d = ad_[node];
    float psum = 0.f;
    for (int k = beg + lane; k < end; k += 8) {
        float e = __expf(leaky02(as_[srcs[k]] + ad_d));
        ew[k] = e;
        psum += e;
    }
#pragma unroll
    for (int off = 4; off > 0; off >>= 1) psum += __shfl_xor(psum, off, 64);
    if (lane == 0) {
        float se = __expf(leaky02(as_[node] + ad_d));
        float r = 1.0f / (psum + se);
        rdn_[node] = r;
        sw_[node] = se * r;
    }
}

// ---------------- bf16 gather v19: LDS-staged + pk math, XCD-pinned slices ----
// H channel-blocked [NCB][n][32]. Block = (cb, node-group of 64); cb pinned to
// XCDs via blockIdx%8 so each XCD's L2 holds one 3.2MB slice. 4 lanes/node,
// u32x4 (16B) per lane per edge; srcs/ew staged once into LDS (coalesced).
// MODE 0: SAGE mean; 1: GCN relu; 2: GAT (precomputed ew/rden/sw); 3: GCN out.
template<int MODE, bool OV>
__device__ __forceinline__ void gath_loop(
    const char* __restrict__ Hb, unsigned loff,
    const int* __restrict__ srcs, const float* __restrict__ ew,
    const int* lsrc, const float* lw,
    int beg, int end, int beg_blk, f32x2* acc)
{
    int k = beg;
    for (; k + 8 <= end; k += 8) {
        int s[8]; float wv[8];
#pragma unroll
        for (int j = 0; j < 8; j++) {
            int ofs = k + j - beg_blk;
            if (OV) {
                bool in = ofs < CAPE;
                int ofc = in ? ofs : 0;
                s[j] = in ? lsrc[ofc] : srcs[k + j];
                if (MODE == 2) wv[j] = in ? lw[ofc] : ew[k + j];
            } else {
                s[j] = lsrc[ofs];
                if (MODE == 2) wv[j] = lw[ofs];
            }
        }
        u32x4 h[8];
#pragma unroll
        for (int j = 0; j < 8; j++)
            h[j] = *(const u32x4*)(Hb + (size_t)(((unsigned)s[j] << 6) + loff));
#pragma unroll
        for (int j = 0; j < 8; j++) {
            f32x2 w2 = {wv[j], wv[j]};
#pragma unroll
            for (int c = 0; c < 4; c++) {
                f32x2 hv = {bflo(h[j][c]), bfhi(h[j][c])};
                if (MODE == 2) acc[c] = w2 * hv + acc[c];   // v_pk_fma_f32
                else           acc[c] = acc[c] + hv;        // v_pk_add_f32
            }
        }
    }
    if (k < end) {
        // masked tail: idx clamped to valid edge, weight zeroed
        int s[8]; float wv[8];
#pragma unroll
        for (int j = 0; j < 8; j++) {
            int kk = k + j;
            bool act = kk < end;
            int kc = act ? kk : end - 1;
            int ofs = kc - beg_blk;
            int sj; float w0 = 1.0f;
            if (OV) {
                bool in = ofs < CAPE;
                int ofc = in ? ofs : 0;
                sj = in ? lsrc[ofc] : srcs[kc];
                if (MODE == 2) w0 = in ? lw[ofc] : ew[kc];
            } else {
                sj = lsrc[ofs];
                if (MODE == 2) w0 = lw[ofs];
            }
            s[j] = sj;
            wv[j] = act ? ((MODE == 2) ? w0 : 1.0f) : 0.0f;
        }
        u32x4 h[8];
#pragma unroll
        for (int j = 0; j < 8; j++)
            h[j] = *(const u32x4*)(Hb + (size_t)(((unsigned)s[j] << 6) + loff));
#pragma unroll
        for (int j = 0; j < 8; j++) {
            f32x2 w2 = {wv[j], wv[j]};
#pragma unroll
            for (int c = 0; c < 4; c++) {
                f32x2 hv = {bflo(h[j][c]), bfhi(h[j][c])};
                acc[c] = w2 * hv + acc[c];
            }
        }
    }
}

template<int NCB, int MODE>
__global__ __launch_bounds__(256) void gatherbf_k(
    const unsigned short* __restrict__ H16, float* __restrict__ outf,
    unsigned short* __restrict__ out16,
    const int* __restrict__ rowptr, const int* __restrict__ srcs,
    const float* __restrict__ scl,   // MODE0: invm; MODE1/3: dinv; MODE2: rdn_
    const float* __restrict__ sw_,   // MODE2: self-alpha
    const float* __restrict__ ew,    // MODE2: per-edge exp weights
    const float* __restrict__ bias, int n)
{
    constexpr int XPC = 8 / NCB;     // XCDs per channel-slice
    constexpr int NPB = 64;          // nodes per block
    __shared__ int lsrc[CAPE];
    __shared__ float lw[(MODE == 2) ? CAPE : 1];

    const int bid = (int)blockIdx.x;
    const int xj = bid & 7;
    const int cb = xj / XPC;
    const int NG = (n + NPB - 1) / NPB;
    const int ng = (bid >> 3) * XPC + (xj % XPC);
    if (ng >= NG) return;

    const int tid = (int)threadIdx.x;
    const int node0 = ng * NPB;
    const int nodeN = min(node0 + NPB, n);
    const int beg_blk = rowptr[node0];
    const int end_blk = rowptr[nodeN];
    const int cnt = end_blk - beg_blk;
    const int cl = min(cnt, CAPE);
    for (int i = tid; i < cl; i += 256) {
        lsrc[i] = srcs[beg_blk + i];
        if (MODE == 2) lw[i] = ew[beg_blk + i];
    }
    __syncthreads();

    const int node = node0 + (tid >> 2);
    const int lane = tid & 3;
    if (node >= nodeN) return;
    const int beg = rowptr[node], end = rowptr[node + 1];
    const char* __restrict__ Hb = (const char*)H16 + (size_t)cb * n * 64;
    const unsigned loff = (unsigned)lane * 16u;

    f32x2 acc[4];
#pragma unroll
    for (int c = 0; c < 4; c++) acc[c] = {0.f, 0.f};

    if (cnt <= CAPE)
        gath_loop<MODE, false>(Hb, loff, srcs, ew, lsrc, lw, beg, end, beg_blk, acc);
    else
        gath_loop<MODE, true>(Hb, loff, srcs, ew, lsrc, lw, beg, end, beg_blk, acc);

    const size_t orow = ((size_t)cb * n + node) * 4 + lane;   // u16x8 units
    float r[8];
    if (MODE == 0) {
        float sc = scl[node];
#pragma unroll
        for (int c = 0; c < 4; c++) { r[2*c] = acc[c].x * sc; r[2*c+1] = acc[c].y * sc; }
    } else {
        u32x4 su = *(const u32x4*)(Hb + (size_t)(((unsigned)node << 6) + loff));
        float sv[8];
#pragma unroll
        for (int c = 0; c < 4; c++) { sv[2*c] = bflo(su[c]); sv[2*c+1] = bfhi(su[c]); }
        const float4* b4 = (const float4*)bias;
        float4 ba = b4[cb * 8 + lane * 2], bb = b4[cb * 8 + lane * 2 + 1];
        float bv[8] = {ba.x, ba.y, ba.z, ba.w, bb.x, bb.y, bb.z, bb.w};
        float a8[8];
#pragma unroll
        for (int c = 0; c < 4; c++) { a8[2*c] = acc[c].x; a8[2*c+1] = acc[c].y; }
        if (MODE == 2) {
            float rden = scl[node], sw = sw_[node];
#pragma unroll
            for (int j = 0; j < 8; j++)
                r[j] = fmaxf(fmaf(rden, a8[j], fmaf(sw, sv[j], bv[j])), 0.f);
        } else {
            float dv = scl[node];
#pragma unroll
            for (int j = 0; j < 8; j++) {
                r[j] = dv * (a8[j] + sv[j]) + bv[j];
                if (MODE == 1) r[j] = fmaxf(r[j], 0.f);
            }
        }
    }
    if (MODE == 3) {
        float4* o4 = (float4*)(outf + (size_t)node * 64 + cb * 32 + lane * 8);
        float4 ra = {r[0], r[1], r[2], r[3]}, rb = {r[4], r[5], r[6], r[7]};
        o4[0] = ra; o4[1] = rb;
    } else {
        u16x8 qv;
#pragma unroll
        for (int j = 0; j < 8; j++) qv[j] = f2bf(r[j]);
        ((u16x8*)out16)[orow] = qv;
    }
}

// ---------------------------------------------------------------------------
extern "C" void kernel_launch(void* const* d_in, const int* in_sizes, int n_in,
                              void* d_out, int out_size, void* d_ws, size_t ws_size,
                              hipStream_t stream)
{
    const float* x   = (const float*)d_in[0];
    const int*   ei  = (const int*)d_in[1];
    const float* W1  = (const float*)d_in[2];
    const float* b1  = (const float*)d_in[3];
    const float* Wl  = (const float*)d_in[4];
    const float* Wr  = (const float*)d_in[5];
    const float* bs  = (const float*)d_in[6];
    const float* Wg  = (const float*)d_in[7];
    const float* a_s = (const float*)d_in[8];
    const float* a_d = (const float*)d_in[9];
    const float* bg  = (const float*)d_in[10];
    const float* Wo  = (const float*)d_in[11];
    const float* bo  = (const float*)d_in[12];

    const int n  = in_sizes[0] / 128;
    const int nE = in_sizes[1] / 2;
    const int* src = ei;
    const int* dst = ei + nE;

    char* w = (char*)d_ws;
    auto alloc = [&](size_t bytes) { char* p = w; w += (bytes + 255) & ~(size_t)255; return p; };
    unsigned short* S0 = (unsigned short*)alloc((size_t)n * 128 * 2);
    unsigned short* S1 = (unsigned short*)alloc((size_t)n * 128 * 2);
    unsigned short* S2 = (unsigned short*)alloc((size_t)n * 128 * 2);
    const int nbv = (n + BUCKET_SZ - 1) / BUCKET_SZ;
    unsigned long long* part = (unsigned long long*)alloc((size_t)nbv * CAP * 8);
    int*   srcs   = (int*)alloc((size_t)nE * 4);
    float* ew     = (float*)alloc((size_t)nE * 4);
    int*   rowptr = (int*)alloc((size_t)(n + 1) * 4);
    int*   bofs   = (int*)alloc((NBMAX + 1) * 4);
    int*   bcur   = (int*)alloc(NBMAX * 4);
    float* dinv   = (float*)alloc((size_t)n * 4);
    float* invm   = (float*)alloc((size_t)n * 4);
    float* as_    = (float*)alloc((size_t)n * 4);
    float* ad_    = (float*)alloc((size_t)n * 4);
    float* rdn_   = (float*)alloc((size_t)n * 4);
    float* sw_    = (float*)alloc((size_t)n * 4);
    unsigned* P1  = (unsigned*)alloc(64 * 128 * 4);
    unsigned* Pl  = (unsigned*)alloc(64 * 128 * 4);
    unsigned* Pr  = (unsigned*)alloc(64 * 128 * 4);
    unsigned* Pg  = (unsigned*)alloc(64 * 128 * 4);
    unsigned* Po  = (unsigned*)alloc(64 * 64 * 4);

    const int TB = 256;
    auto cdiv = [](long long a, long long b) { return (int)((a + b - 1) / b); };
    const int nb     = nbv;
    const int gPart  = cdiv(nE, PART_CH);
    const int gGemm  = cdiv(n, 64);
    const int NG     = cdiv(n, 64);            // node-groups of 64
    const int gGa128 = 8 * cdiv(NG, 2);        // NCB=4, 2 XCDs per slice
    const int gGa64  = 8 * cdiv(NG, 4);        // NCB=2, 4 XCDs per slice
    const int gGatw  = cdiv(n, 32);

    // ---- weight pre-pack (once) + bucket CSR build (LDS atomics only)
    wpackall_k<<<5, TB, 0, stream>>>(W1, Wl, Wr, Wg, Wo, P1, Pl, Pr, Pg, Po);
    binit_k<<<1, 256, 0, stream>>>(bcur, nb);
    part_k<<<gPart, TB, 0, stream>>>(src, dst, bcur, part, nE);
    bscan_k<<<1, 256, 0, stream>>>(bcur, bofs, nb);
    csr_k<<<nb, TB, 0, stream>>>(part, bcur, bofs, rowptr, srcs, dinv, invm, n, nE);

    // ---- Layer 1: GCN — x@W1 scaled by dinv[row] -> S0; gather -> S1 (=h1)
    mgemm_k<128, true, true, false, false, false><<<gGemm, TB, 0, stream>>>(
        x, (const unsigned short*)P1, nullptr, nullptr, S0, dinv, nullptr,
        nullptr, nullptr, nullptr, nullptr, n);
    gatherbf_k<4, 1><<<gGa128, TB, 0, stream>>>(S0, nullptr, S1, rowptr, srcs,
                                                dinv, nullptr, nullptr, b1, n);

    // ---- Layer 2: SAGE — mean(S1) -> S0; dual GEMM mean@Wl + h1@Wr -> S2 (=h2)
    gatherbf_k<4, 0><<<gGa128, TB, 0, stream>>>(S1, nullptr, S0, rowptr, srcs,
                                                invm, nullptr, nullptr, nullptr, n);
    mgemm_k<128, false, false, true, true, false><<<gGemm, TB, 0, stream>>>(
        S0, (const unsigned short*)Pl, S1, (const unsigned short*)Pr, S2,
        nullptr, bs, nullptr, nullptr, nullptr, nullptr, n);

    // ---- Layer 3: GAT — h2@Wg -> S1 (+fused dots); edge weights; gather -> S0
    mgemm_k<128, false, false, false, false, true><<<gGemm, TB, 0, stream>>>(
        S2, (const unsigned short*)Pg, nullptr, nullptr, S1, nullptr, nullptr,
        a_s, a_d, as_, ad_, n);
    gatw_k<<<gGatw, TB, 0, stream>>>(rowptr, srcs, as_, ad_, ew, rdn_, sw_, n);
    gatherbf_k<4, 2><<<gGa128, TB, 0, stream>>>(S1, nullptr, S0, rowptr, srcs,
                                                rdn_, sw_, ew, bg, n);

    // ---- Output: h3@Wo scaled by dinv[row] -> S2; gather -> d_out (fp32)
    mgemm_k<64, false, true, false, false, false><<<gGemm, TB, 0, stream>>>(
        S0, (const unsigned short*)Po, nullptr, nullptr, S2, dinv, nullptr,
        nullptr, nullptr, nullptr, nullptr, n);
    gatherbf_k<2, 3><<<gGa64, TB, 0, stream>>>(S2, (float*)d_out, nullptr, rowptr, srcs,
                                               dinv, nullptr, nullptr, bo, n);
}

// Round 8
// 343.531 us; speedup vs baseline: 1.6707x; 1.0223x over previous
//
#include <hip/hip_runtime.h>
#include <math.h>

// ---------------------------------------------------------------------------
// DynamicGNN: GCN -> SAGE(mean) -> GAT(1 head) -> GCN(128->64)
// N=50000, E=1.6M, D=128, OUT=64.
// v20: gather MLP push — 128-thr/32-node blocks (CAPE 1280, 5-10KB LDS),
//      explicit 16-deep h-load batches (2x loads in flight/wave), launch
//      bounds relaxed for ~128 VGPR. Dispatch trim: binit folded into
//      wpackall (6 blocks), bucket scan inlined into csr_k. Rest = v19
//      (prepacked-weight no-LDS GEMMs, staged+XCD-pinned gathers).
//      11 dispatches total.
// ---------------------------------------------------------------------------

#define BUCKET_BITS 8
#define BUCKET_SZ   256
#define NBMAX       256
#define CAP         10240   // padded bucket capacity (~8163 +- 90 expected)
#define CAPE        1280    // staged edges per 32-node block (mean 1024 + 8 sigma)

typedef short short8 __attribute__((ext_vector_type(8)));
typedef float f32x4 __attribute__((ext_vector_type(4)));
typedef float f32x2 __attribute__((ext_vector_type(2)));
typedef unsigned int u32x4 __attribute__((ext_vector_type(4)));
typedef unsigned short u16x8 __attribute__((ext_vector_type(8)));

__device__ __forceinline__ float leaky02(float x) { return x > 0.0f ? x : 0.2f * x; }
__device__ __forceinline__ float bflo(unsigned u) { return __uint_as_float(u << 16); }
__device__ __forceinline__ float bfhi(unsigned u) { return __uint_as_float(u & 0xFFFF0000u); }
__device__ __forceinline__ unsigned short f2bf(float f) {
    unsigned u = __float_as_uint(f);
    u += 0x7FFFu + ((u >> 16) & 1u);   // round-to-nearest-even
    return (unsigned short)(u >> 16);
}

// ---------------- weight pre-pack + bucket-cursor init (one dispatch, 6 blk)
__global__ __launch_bounds__(256) void wpackall_k(
    const float* __restrict__ W1, const float* __restrict__ Wl,
    const float* __restrict__ Wr, const float* __restrict__ Wg,
    const float* __restrict__ Wo,
    unsigned* __restrict__ P1, unsigned* __restrict__ Pl,
    unsigned* __restrict__ Pr, unsigned* __restrict__ Pg,
    unsigned* __restrict__ Po, int* __restrict__ bcur, int nb)
{
    const int b = blockIdx.x;
    if (b == 5) {                       // binit
        int t = threadIdx.x;
        if (t < nb) bcur[t] = t * CAP;
        return;
    }
    const float* W; unsigned* P; int NO;
    if      (b == 0) { W = W1; P = P1; NO = 128; }
    else if (b == 1) { W = Wl; P = Pl; NO = 128; }
    else if (b == 2) { W = Wr; P = Pr; NO = 128; }
    else if (b == 3) { W = Wg; P = Pg; NO = 128; }
    else             { W = Wo; P = Po; NO = 64;  }
    const int CT = NO / 16;
    const int n4w = NO / 4;
    for (int f = threadIdx.x; f < 64 * n4w; f += 256) {
        const int kp = f / n4w;
        const int n4 = f % n4w;
        const float4 a = *(const float4*)(W + (size_t)(2 * kp) * NO + n4 * 4);
        const float4 bb = *(const float4*)(W + (size_t)(2 * kp + 1) * NO + n4 * 4);
        const int k = 2 * kp, kb = k >> 5, qq = (k >> 3) & 3, p = (k & 7) >> 1;
        const float av[4] = {a.x, a.y, a.z, a.w};
        const float bv[4] = {bb.x, bb.y, bb.z, bb.w};
#pragma unroll
        for (int j = 0; j < 4; j++) {
            int col = n4 * 4 + j;
            int c = col >> 4, nl = col & 15;
            unsigned pk = (unsigned)f2bf(av[j]) | ((unsigned)f2bf(bv[j]) << 16);
            P[(((kb * CT + c) * 64) + qq * 16 + nl) * 4 + p] = pk;
        }
    }
}

// ---------------- MFMA GEMM: B-frags direct from prepacked global -----------
// 256 thr = 4 waves; block = 64 rows; wave = 16 rows x NO cols. No LDS, no
// barriers. bf16 A channel-blocked [kb][n][32]; fp32 A (layer 1) node-major.
// C16 written channel-blocked [col>>5][n][32].
template<int NO, bool AFP32, bool SCALE, bool BIASRELU, bool DUAL, bool DOTS>
__global__ __launch_bounds__(256) void mgemm_k(
    const void* __restrict__ Av, const unsigned short* __restrict__ Bp,
    const void* __restrict__ A1v, const unsigned short* __restrict__ Bp1,
    unsigned short* __restrict__ C16,
    const float* __restrict__ scale, const float* __restrict__ bias,
    const float* __restrict__ a_s, const float* __restrict__ a_d,
    float* __restrict__ as_, float* __restrict__ ad_, int n)
{
    constexpr int CT = NO / 16;
    const int tid = threadIdx.x;
    const int wave = tid >> 6, lane = tid & 63;
    const int q = lane >> 4, ml = lane & 15;
    const int row0 = blockIdx.x * 64 + wave * 16;
    int arow = row0 + ml; if (arow >= n) arow = n - 1;

    f32x4 acc[CT];
#pragma unroll
    for (int c = 0; c < CT; c++) acc[c] = {0.f, 0.f, 0.f, 0.f};

    for (int half = 0; half < (DUAL ? 2 : 1); half++) {
        const unsigned short* __restrict__ Bsrc = half ? Bp1 : Bp;
        const void* Asrc = half ? A1v : Av;
#pragma unroll
        for (int kb = 0; kb < 4; kb++) {
            short8 afr;
            if (AFP32) {
                const float* Af = (const float*)Asrc + (size_t)arow * 128 + kb * 32 + q * 8;
                float4 f0 = *(const float4*)Af;
                float4 f1 = *(const float4*)(Af + 4);
                afr[0] = (short)f2bf(f0.x); afr[1] = (short)f2bf(f0.y);
                afr[2] = (short)f2bf(f0.z); afr[3] = (short)f2bf(f0.w);
                afr[4] = (short)f2bf(f1.x); afr[5] = (short)f2bf(f1.y);
                afr[6] = (short)f2bf(f1.z); afr[7] = (short)f2bf(f1.w);
            } else {
                afr = *(const short8*)((const unsigned short*)Asrc +
                                       ((size_t)kb * n + arow) * 32 + q * 8);
            }
            short8 bfr[CT];
#pragma unroll
            for (int c = 0; c < CT; c++)
                bfr[c] = *(const short8*)(Bsrc + ((size_t)(kb * CT + c) * 64 + lane) * 8);
#pragma unroll
            for (int c = 0; c < CT; c++)
                acc[c] = __builtin_amdgcn_mfma_f32_16x16x32_bf16(afr, bfr[c], acc[c], 0, 0, 0);
        }
    }

    if (DOTS) {
        float ps[4] = {0.f, 0.f, 0.f, 0.f}, pd[4] = {0.f, 0.f, 0.f, 0.f};
#pragma unroll
        for (int c = 0; c < CT; c++) {
            float sv = a_s[c * 16 + ml], dv = a_d[c * 16 + ml];
#pragma unroll
            for (int r = 0; r < 4; r++) {
                ps[r] = fmaf(acc[c][r], sv, ps[r]);
                pd[r] = fmaf(acc[c][r], dv, pd[r]);
            }
        }
#pragma unroll
        for (int off = 1; off < 16; off <<= 1) {
#pragma unroll
            for (int r = 0; r < 4; r++) {
                ps[r] += __shfl_xor(ps[r], off, 64);
                pd[r] += __shfl_xor(pd[r], off, 64);
            }
        }
        if (ml == 0) {
#pragma unroll
            for (int r = 0; r < 4; r++) {
                int row = row0 + q * 4 + r;
                if (row < n) { as_[row] = ps[r]; ad_[row] = pd[r]; }
            }
        }
    }

    float sc[4];
    if (SCALE) {
#pragma unroll
        for (int r = 0; r < 4; r++) {
            int row = row0 + q * 4 + r;
            sc[r] = scale[row < n ? row : 0];
        }
    }
#pragma unroll
    for (int c = 0; c < CT; c++) {
        float bv = BIASRELU ? bias[c * 16 + ml] : 0.0f;
        const int col = c * 16 + ml;
#pragma unroll
        for (int r = 0; r < 4; r++) {
            int row = row0 + q * 4 + r;
            if (row < n) {
                float v = acc[c][r];
                if (SCALE) v *= sc[r];
                if (BIASRELU) v = fmaxf(v + bv, 0.0f);
                C16[((size_t)(col >> 5) * n + row) * 32 + (col & 31)] = f2bf(v);
            }
        }
    }
}

// ---------------- CSR build: padded buckets (LDS atomics only) ----------------
#define PART_CH 4096
__global__ __launch_bounds__(256) void part_k(
    const int* __restrict__ src, const int* __restrict__ dst,
    int* __restrict__ bcur, unsigned long long* __restrict__ part, int nE)
{
    __shared__ int cnt[NBMAX];
    __shared__ int cur[NBMAX];
    const int base = blockIdx.x * PART_CH;
    const int t = threadIdx.x;
    cnt[t] = 0;
    __syncthreads();
    int d[PART_CH / 256], s[PART_CH / 256];
#pragma unroll
    for (int j = 0; j < PART_CH / 256; j++) {
        int e = base + j * 256 + t;
        if (e < nE) {
            d[j] = dst[e]; s[j] = src[e];
            atomicAdd(&cnt[d[j] >> BUCKET_BITS], 1);
        } else d[j] = -1;
    }
    __syncthreads();
    {
        int c = cnt[t];
        cur[t] = c ? atomicAdd(&bcur[t], c) : 0;
    }
    __syncthreads();
#pragma unroll
    for (int j = 0; j < PART_CH / 256; j++) {
        if (d[j] >= 0) {
            int p = atomicAdd(&cur[d[j] >> BUCKET_BITS], 1);
            part[p] = ((unsigned long long)(unsigned)d[j] << 32) | (unsigned)s[j];
        }
    }
}

// per-bucket CSR finalize; bucket-base scan inlined (196-entry LDS scan/block)
__global__ __launch_bounds__(256) void csr_k(
    const unsigned long long* __restrict__ part, const int* __restrict__ bcur,
    int* __restrict__ rowptr, int* __restrict__ srcs,
    float* __restrict__ dinv, float* __restrict__ invm, int n, int nE, int nb)
{
    __shared__ int lcnt[BUCKET_SZ];
    __shared__ int sm[BUCKET_SZ];
    __shared__ int lcur[BUCKET_SZ];
    const int b = blockIdx.x;
    const int t = threadIdx.x;
    const int base_in = b * CAP;
    const int cntE = bcur[b] - base_in;

    // inlined bucket scan: base_out = sum of counts of buckets < b
    int vb = (t < nb) ? (bcur[t] - t * CAP) : 0;
    sm[t] = vb;
    __syncthreads();
    for (int off = 1; off < 256; off <<= 1) {
        int tv = (t >= off) ? sm[t - off] : 0;
        __syncthreads();
        sm[t] += tv;
        __syncthreads();
    }
    const int base_out = sm[b] - (bcur[b] - b * CAP);
    __syncthreads();

    lcnt[t] = 0;
    __syncthreads();
#pragma unroll 4
    for (int e = t; e < cntE; e += 256) {
        int dl = (int)(part[base_in + e] >> 32) & (BUCKET_SZ - 1);
        atomicAdd(&lcnt[dl], 1);
    }
    __syncthreads();
    int v = lcnt[t];
    sm[t] = v;
    __syncthreads();
    for (int off = 1; off < 256; off <<= 1) {
        int tv = (t >= off) ? sm[t - off] : 0;
        __syncthreads();
        sm[t] += tv;
        __syncthreads();
    }
    const int excl = sm[t] - v;
    const int node = (b << BUCKET_BITS) + t;
    if (node < n) {
        rowptr[node] = base_out + excl;
        float dg = (float)v;
        dinv[node] = rsqrtf(dg + 1.0f);
        invm[node] = 1.0f / fmaxf(dg, 1.0f);
        if (node == n - 1) rowptr[n] = nE;
    }
    lcur[t] = excl;
    __syncthreads();
#pragma unroll 4
    for (int e = t; e < cntE; e += 256) {
        unsigned long long w = part[base_in + e];
        int dl = (int)(w >> 32) & (BUCKET_SZ - 1);
        int pos = atomicAdd(&lcur[dl], 1);
        srcs[base_out + pos] = (int)(unsigned)w;
    }
}

// ---------------- GAT edge-weight precompute: ew[e], rdn_[node], sw_[node] ----
__global__ __launch_bounds__(256) void gatw_k(
    const int* __restrict__ rowptr, const int* __restrict__ srcs,
    const float* __restrict__ as_, const float* __restrict__ ad_,
    float* __restrict__ ew, float* __restrict__ rdn_, float* __restrict__ sw_, int n)
{
    const int node = blockIdx.x * 32 + (threadIdx.x >> 3);
    const int lane = threadIdx.x & 7;
    if (node >= n) return;
    const int beg = rowptr[node], end = rowptr[node + 1];
    const float ad_d = ad_[node];
    float psum = 0.f;
    for (int k = beg + lane; k < end; k += 8) {
        float e = __expf(leaky02(as_[srcs[k]] + ad_d));
        ew[k] = e;
        psum += e;
    }
#pragma unroll
    for (int off = 4; off > 0; off >>= 1) psum += __shfl_xor(psum, off, 64);
    if (lane == 0) {
        float se = __expf(leaky02(as_[node] + ad_d));
        float r = 1.0f / (psum + se);
        rdn_[node] = r;
        sw_[node] = se * r;
    }
}

// ---------------- bf16 gather v20: 128-thr/32-node blocks, 16-deep loads ------
// H channel-blocked [NCB][n][32]. Block = (cb, node-group of 32); cb pinned to
// XCDs via blockIdx%8. 4 lanes/node, u32x4 per lane per edge; srcs/ew staged
// once into LDS (coalesced). 16 h-loads in flight before consumption.
// MODE 0: SAGE mean; 1: GCN relu; 2: GAT (precomputed ew/rden/sw); 3: GCN out.
template<int MODE, bool OV>
__device__ __forceinline__ void gath_loop(
    const char* __restrict__ Hb, unsigned loff,
    const int* __restrict__ srcs, const float* __restrict__ ew,
    const int* lsrc, const float* lw,
    int beg, int end, int beg_blk, f32x2* acc)
{
    int k = beg;
    for (; k + 16 <= end; k += 16) {
        int s[16]; float wv[16];
#pragma unroll
        for (int j = 0; j < 16; j++) {
            int ofs = k + j - beg_blk;
            if (OV) {
                bool in = ofs < CAPE;
                int ofc = in ? ofs : 0;
                s[j] = in ? lsrc[ofc] : srcs[k + j];
                if (MODE == 2) wv[j] = in ? lw[ofc] : ew[k + j];
            } else {
                s[j] = lsrc[ofs];
                if (MODE == 2) wv[j] = lw[ofs];
            }
        }
        u32x4 h[16];
#pragma unroll
        for (int j = 0; j < 16; j++)
            h[j] = *(const u32x4*)(Hb + (size_t)(((unsigned)s[j] << 6) + loff));
#pragma unroll
        for (int j = 0; j < 16; j++) {
            f32x2 w2 = {wv[j], wv[j]};
#pragma unroll
            for (int c = 0; c < 4; c++) {
                f32x2 hv = {bflo(h[j][c]), bfhi(h[j][c])};
                if (MODE == 2) acc[c] = w2 * hv + acc[c];   // v_pk_fma_f32
                else           acc[c] = acc[c] + hv;        // v_pk_add_f32
            }
        }
    }
    for (; k + 8 <= end; k += 8) {
        int s[8]; float wv[8];
#pragma unroll
        for (int j = 0; j < 8; j++) {
            int ofs = k + j - beg_blk;
            if (OV) {
                bool in = ofs < CAPE;
                int ofc = in ? ofs : 0;
                s[j] = in ? lsrc[ofc] : srcs[k + j];
                if (MODE == 2) wv[j] = in ? lw[ofc] : ew[k + j];
            } else {
                s[j] = lsrc[ofs];
                if (MODE == 2) wv[j] = lw[ofs];
            }
        }
        u32x4 h[8];
#pragma unroll
        for (int j = 0; j < 8; j++)
            h[j] = *(const u32x4*)(Hb + (size_t)(((unsigned)s[j] << 6) + loff));
#pragma unroll
        for (int j = 0; j < 8; j++) {
            f32x2 w2 = {wv[j], wv[j]};
#pragma unroll
            for (int c = 0; c < 4; c++) {
                f32x2 hv = {bflo(h[j][c]), bfhi(h[j][c])};
                if (MODE == 2) acc[c] = w2 * hv + acc[c];
                else           acc[c] = acc[c] + hv;
            }
        }
    }
    if (k < end) {
        // masked tail: idx clamped to valid edge, weight zeroed
        int s[8]; float wv[8];
#pragma unroll
        for (int j = 0; j < 8; j++) {
            int kk = k + j;
            bool act = kk < end;
            int kc = act ? kk : end - 1;
            int ofs = kc - beg_blk;
            int sj; float w0 = 1.0f;
            if (OV) {
                bool in = ofs < CAPE;
                int ofc = in ? ofs : 0;
                sj = in ? lsrc[ofc] : srcs[kc];
                if (MODE == 2) w0 = in ? lw[ofc] : ew[kc];
            } else {
                sj = lsrc[ofs];
                if (MODE == 2) w0 = lw[ofs];
            }
            s[j] = sj;
            wv[j] = act ? ((MODE == 2) ? w0 : 1.0f) : 0.0f;
        }
        u32x4 h[8];
#pragma unroll
        for (int j = 0; j < 8; j++)
            h[j] = *(const u32x4*)(Hb + (size_t)(((unsigned)s[j] << 6) + loff));
#pragma unroll
        for (int j = 0; j < 8; j++) {
            f32x2 w2 = {wv[j], wv[j]};
#pragma unroll
            for (int c = 0; c < 4; c++) {
                f32x2 hv = {bflo(h[j][c]), bfhi(h[j][c])};
                acc[c] = w2 * hv + acc[c];
            }
        }
    }
}

template<int NCB, int MODE>
__global__ __launch_bounds__(128, 4) void gatherbf_k(
    const unsigned short* __restrict__ H16, float* __restrict__ outf,
    unsigned short* __restrict__ out16,
    const int* __restrict__ rowptr, const int* __restrict__ srcs,
    const float* __restrict__ scl,   // MODE0: invm; MODE1/3: dinv; MODE2: rdn_
    const float* __restrict__ sw_,   // MODE2: self-alpha
    const float* __restrict__ ew,    // MODE2: per-edge exp weights
    const float* __restrict__ bias, int n)
{
    constexpr int XPC = 8 / NCB;     // XCDs per channel-slice
    constexpr int NPB = 32;          // nodes per block
    __shared__ int lsrc[CAPE];
    __shared__ float lw[(MODE == 2) ? CAPE : 1];

    const int bid = (int)blockIdx.x;
    const int xj = bid & 7;
    const int cb = xj / XPC;
    const int NG = (n + NPB - 1) / NPB;
    const int ng = (bid >> 3) * XPC + (xj % XPC);
    if (ng >= NG) return;

    const int tid = (int)threadIdx.x;
    const int node0 = ng * NPB;
    const int nodeN = min(node0 + NPB, n);
    const int beg_blk = rowptr[node0];
    const int end_blk = rowptr[nodeN];
    const int cnt = end_blk - beg_blk;
    const int cl = min(cnt, CAPE);
    for (int i = tid; i < cl; i += 128) {
        lsrc[i] = srcs[beg_blk + i];
        if (MODE == 2) lw[i] = ew[beg_blk + i];
    }
    __syncthreads();

    const int node = node0 + (tid >> 2);
    const int lane = tid & 3;
    if (node >= nodeN) return;
    const int beg = rowptr[node], end = rowptr[node + 1];
    const char* __restrict__ Hb = (const char*)H16 + (size_t)cb * n * 64;
    const unsigned loff = (unsigned)lane * 16u;

    f32x2 acc[4];
#pragma unroll
    for (int c = 0; c < 4; c++) acc[c] = {0.f, 0.f};

    if (cnt <= CAPE)
        gath_loop<MODE, false>(Hb, loff, srcs, ew, lsrc, lw, beg, end, beg_blk, acc);
    else
        gath_loop<MODE, true>(Hb, loff, srcs, ew, lsrc, lw, beg, end, beg_blk, acc);

    const size_t orow = ((size_t)cb * n + node) * 4 + lane;   // u16x8 units
    float r[8];
    if (MODE == 0) {
        float sc = scl[node];
#pragma unroll
        for (int c = 0; c < 4; c++) { r[2*c] = acc[c].x * sc; r[2*c+1] = acc[c].y * sc; }
    } else {
        u32x4 su = *(const u32x4*)(Hb + (size_t)(((unsigned)node << 6) + loff));
        float sv[8];
#pragma unroll
        for (int c = 0; c < 4; c++) { sv[2*c] = bflo(su[c]); sv[2*c+1] = bfhi(su[c]); }
        const float4* b4 = (const float4*)bias;
        float4 ba = b4[cb * 8 + lane * 2], bb = b4[cb * 8 + lane * 2 + 1];
        float bv[8] = {ba.x, ba.y, ba.z, ba.w, bb.x, bb.y, bb.z, bb.w};
        float a8[8];
#pragma unroll
        for (int c = 0; c < 4; c++) { a8[2*c] = acc[c].x; a8[2*c+1] = acc[c].y; }
        if (MODE == 2) {
            float rden = scl[node], sw = sw_[node];
#pragma unroll
            for (int j = 0; j < 8; j++)
                r[j] = fmaxf(fmaf(rden, a8[j], fmaf(sw, sv[j], bv[j])), 0.f);
        } else {
            float dv = scl[node];
#pragma unroll
            for (int j = 0; j < 8; j++) {
                r[j] = dv * (a8[j] + sv[j]) + bv[j];
                if (MODE == 1) r[j] = fmaxf(r[j], 0.f);
            }
        }
    }
    if (MODE == 3) {
        float4* o4 = (float4*)(outf + (size_t)node * 64 + cb * 32 + lane * 8);
        float4 ra = {r[0], r[1], r[2], r[3]}, rb = {r[4], r[5], r[6], r[7]};
        o4[0] = ra; o4[1] = rb;
    } else {
        u16x8 qv;
#pragma unroll
        for (int j = 0; j < 8; j++) qv[j] = f2bf(r[j]);
        ((u16x8*)out16)[orow] = qv;
    }
}

// ---------------------------------------------------------------------------
extern "C" void kernel_launch(void* const* d_in, const int* in_sizes, int n_in,
                              void* d_out, int out_size, void* d_ws, size_t ws_size,
                              hipStream_t stream)
{
    const float* x   = (const float*)d_in[0];
    const int*   ei  = (const int*)d_in[1];
    const float* W1  = (const float*)d_in[2];
    const float* b1  = (const float*)d_in[3];
    const float* Wl  = (const float*)d_in[4];
    const float* Wr  = (const float*)d_in[5];
    const float* bs  = (const float*)d_in[6];
    const float* Wg  = (const float*)d_in[7];
    const float* a_s = (const float*)d_in[8];
    const float* a_d = (const float*)d_in[9];
    const float* bg  = (const float*)d_in[10];
    const float* Wo  = (const float*)d_in[11];
    const float* bo  = (const float*)d_in[12];

    const int n  = in_sizes[0] / 128;
    const int nE = in_sizes[1] / 2;
    const int* src = ei;
    const int* dst = ei + nE;

    char* w = (char*)d_ws;
    auto alloc = [&](size_t bytes) { char* p = w; w += (bytes + 255) & ~(size_t)255; return p; };
    unsigned short* S0 = (unsigned short*)alloc((size_t)n * 128 * 2);
    unsigned short* S1 = (unsigned short*)alloc((size_t)n * 128 * 2);
    unsigned short* S2 = (unsigned short*)alloc((size_t)n * 128 * 2);
    const int nbv = (n + BUCKET_SZ - 1) / BUCKET_SZ;
    unsigned long long* part = (unsigned long long*)alloc((size_t)nbv * CAP * 8);
    int*   srcs   = (int*)alloc((size_t)nE * 4);
    float* ew     = (float*)alloc((size_t)nE * 4);
    int*   rowptr = (int*)alloc((size_t)(n + 1) * 4);
    int*   bcur   = (int*)alloc(NBMAX * 4);
    float* dinv   = (float*)alloc((size_t)n * 4);
    float* invm   = (float*)alloc((size_t)n * 4);
    float* as_    = (float*)alloc((size_t)n * 4);
    float* ad_    = (float*)alloc((size_t)n * 4);
    float* rdn_   = (float*)alloc((size_t)n * 4);
    float* sw_    = (float*)alloc((size_t)n * 4);
    unsigned* P1  = (unsigned*)alloc(64 * 128 * 4);
    unsigned* Pl  = (unsigned*)alloc(64 * 128 * 4);
    unsigned* Pr  = (unsigned*)alloc(64 * 128 * 4);
    unsigned* Pg  = (unsigned*)alloc(64 * 128 * 4);
    unsigned* Po  = (unsigned*)alloc(64 * 64 * 4);

    const int TB = 256;
    auto cdiv = [](long long a, long long b) { return (int)((a + b - 1) / b); };
    const int nb     = nbv;
    const int gPart  = cdiv(nE, PART_CH);
    const int gGemm  = cdiv(n, 64);
    const int NG     = cdiv(n, 32);            // node-groups of 32
    const int gGa128 = 8 * cdiv(NG, 2);        // NCB=4, 2 XCDs per slice
    const int gGa64  = 8 * cdiv(NG, 4);        // NCB=2, 4 XCDs per slice
    const int gGatw  = cdiv(n, 32);

    // ---- weight pre-pack + bucket init (1 dispatch) + bucket CSR build
    wpackall_k<<<6, TB, 0, stream>>>(W1, Wl, Wr, Wg, Wo, P1, Pl, Pr, Pg, Po, bcur, nb);
    part_k<<<gPart, TB, 0, stream>>>(src, dst, bcur, part, nE);
    csr_k<<<nb, TB, 0, stream>>>(part, bcur, rowptr, srcs, dinv, invm, n, nE, nb);

    // ---- Layer 1: GCN — x@W1 scaled by dinv[row] -> S0; gather -> S1 (=h1)
    mgemm_k<128, true, true, false, false, false><<<gGemm, TB, 0, stream>>>(
        x, (const unsigned short*)P1, nullptr, nullptr, S0, dinv, nullptr,
        nullptr, nullptr, nullptr, nullptr, n);
    gatherbf_k<4, 1><<<gGa128, 128, 0, stream>>>(S0, nullptr, S1, rowptr, srcs,
                                                 dinv, nullptr, nullptr, b1, n);

    // ---- Layer 2: SAGE — mean(S1) -> S0; dual GEMM mean@Wl + h1@Wr -> S2 (=h2)
    gatherbf_k<4, 0><<<gGa128, 128, 0, stream>>>(S1, nullptr, S0, rowptr, srcs,
                                                 invm, nullptr, nullptr, nullptr, n);
    mgemm_k<128, false, false, true, true, false><<<gGemm, TB, 0, stream>>>(
        S0, (const unsigned short*)Pl, S1, (const unsigned short*)Pr, S2,
        nullptr, bs, nullptr, nullptr, nullptr, nullptr, n);

    // ---- Layer 3: GAT — h2@Wg -> S1 (+fused dots); edge weights; gather -> S0
    mgemm_k<128, false, false, false, false, true><<<gGemm, TB, 0, stream>>>(
        S2, (const unsigned short*)Pg, nullptr, nullptr, S1, nullptr, nullptr,
        a_s, a_d, as_, ad_, n);
    gatw_k<<<gGatw, TB, 0, stream>>>(rowptr, srcs, as_, ad_, ew, rdn_, sw_, n);
    gatherbf_k<4, 2><<<gGa128, 128, 0, stream>>>(S1, nullptr, S0, rowptr, srcs,
                                                 rdn_, sw_, ew, bg, n);

    // ---- Output: h3@Wo scaled by dinv[row] -> S2; gather -> d_out (fp32)
    mgemm_k<64, false, true, false, false, false><<<gGemm, TB, 0, stream>>>(
        S0, (const unsigned short*)Po, nullptr, nullptr, S2, dinv, nullptr,
        nullptr, nullptr, nullptr, nullptr, n);
    gatherbf_k<2, 3><<<gGa64, 128, 0, stream>>>(S2, (float*)d_out, nullptr, rowptr, srcs,
                                                dinv, nullptr, nullptr, bo, n);
}

// Round 9
// 327.020 us; speedup vs baseline: 1.7550x; 1.0505x over previous
//
#include <hip/hip_runtime.h>
#include <math.h>

// ---------------------------------------------------------------------------
// DynamicGNN: GCN -> SAGE(mean) -> GAT(1 head) -> GCN(128->64)
// N=50000, E=1.6M, D=128, OUT=64.
// v21: full-cacheline gathers. Channel blocking 4x32ch -> 2x64ch: each edge
//      read is one aligned 128B request (8 lanes x 16B) instead of 64B —
//      no half-line waste if lines are 128B. 16 nodes/block (128 thr),
//      CAPE 768. 64-ch out gather = single 128B-row slice. GEMM layout
//      re-indexed for [cb][N][64]. Build/gatw/mgemm core = v20.
//      11 dispatches total.
// ---------------------------------------------------------------------------

#define BUCKET_BITS 8
#define BUCKET_SZ   256
#define NBMAX       256
#define CAP         10240   // padded bucket capacity (~8163 +- 90 expected)
#define CAPE        768     // staged edges per 16-node block (mean 512 + 11 sigma)

typedef short short8 __attribute__((ext_vector_type(8)));
typedef float f32x4 __attribute__((ext_vector_type(4)));
typedef float f32x2 __attribute__((ext_vector_type(2)));
typedef unsigned int u32x4 __attribute__((ext_vector_type(4)));
typedef unsigned short u16x8 __attribute__((ext_vector_type(8)));

__device__ __forceinline__ float leaky02(float x) { return x > 0.0f ? x : 0.2f * x; }
__device__ __forceinline__ float bflo(unsigned u) { return __uint_as_float(u << 16); }
__device__ __forceinline__ float bfhi(unsigned u) { return __uint_as_float(u & 0xFFFF0000u); }
__device__ __forceinline__ unsigned short f2bf(float f) {
    unsigned u = __float_as_uint(f);
    u += 0x7FFFu + ((u >> 16) & 1u);   // round-to-nearest-even
    return (unsigned short)(u >> 16);
}

// ---------------- weight pre-pack + bucket-cursor init (one dispatch, 6 blk)
__global__ __launch_bounds__(256) void wpackall_k(
    const float* __restrict__ W1, const float* __restrict__ Wl,
    const float* __restrict__ Wr, const float* __restrict__ Wg,
    const float* __restrict__ Wo,
    unsigned* __restrict__ P1, unsigned* __restrict__ Pl,
    unsigned* __restrict__ Pr, unsigned* __restrict__ Pg,
    unsigned* __restrict__ Po, int* __restrict__ bcur, int nb)
{
    const int b = blockIdx.x;
    if (b == 5) {                       // binit
        int t = threadIdx.x;
        if (t < nb) bcur[t] = t * CAP;
        return;
    }
    const float* W; unsigned* P; int NO;
    if      (b == 0) { W = W1; P = P1; NO = 128; }
    else if (b == 1) { W = Wl; P = Pl; NO = 128; }
    else if (b == 2) { W = Wr; P = Pr; NO = 128; }
    else if (b == 3) { W = Wg; P = Pg; NO = 128; }
    else             { W = Wo; P = Po; NO = 64;  }
    const int CT = NO / 16;
    const int n4w = NO / 4;
    for (int f = threadIdx.x; f < 64 * n4w; f += 256) {
        const int kp = f / n4w;
        const int n4 = f % n4w;
        const float4 a = *(const float4*)(W + (size_t)(2 * kp) * NO + n4 * 4);
        const float4 bb = *(const float4*)(W + (size_t)(2 * kp + 1) * NO + n4 * 4);
        const int k = 2 * kp, kb = k >> 5, qq = (k >> 3) & 3, p = (k & 7) >> 1;
        const float av[4] = {a.x, a.y, a.z, a.w};
        const float bv[4] = {bb.x, bb.y, bb.z, bb.w};
#pragma unroll
        for (int j = 0; j < 4; j++) {
            int col = n4 * 4 + j;
            int c = col >> 4, nl = col & 15;
            unsigned pk = (unsigned)f2bf(av[j]) | ((unsigned)f2bf(bv[j]) << 16);
            P[(((kb * CT + c) * 64) + qq * 16 + nl) * 4 + p] = pk;
        }
    }
}

// ---------------- MFMA GEMM: B-frags direct from prepacked global -----------
// 256 thr = 4 waves; block = 64 rows; wave = 16 rows x NO cols. No LDS, no
// barriers. bf16 A channel-blocked [cb64][n][64]; fp32 A (layer 1) node-major.
// C16 written channel-blocked [col>>6][n][64] (row-major when NO=64).
template<int NO, bool AFP32, bool SCALE, bool BIASRELU, bool DUAL, bool DOTS>
__global__ __launch_bounds__(256) void mgemm_k(
    const void* __restrict__ Av, const unsigned short* __restrict__ Bp,
    const void* __restrict__ A1v, const unsigned short* __restrict__ Bp1,
    unsigned short* __restrict__ C16,
    const float* __restrict__ scale, const float* __restrict__ bias,
    const float* __restrict__ a_s, const float* __restrict__ a_d,
    float* __restrict__ as_, float* __restrict__ ad_, int n)
{
    constexpr int CT = NO / 16;
    const int tid = threadIdx.x;
    const int wave = tid >> 6, lane = tid & 63;
    const int q = lane >> 4, ml = lane & 15;
    const int row0 = blockIdx.x * 64 + wave * 16;
    int arow = row0 + ml; if (arow >= n) arow = n - 1;

    f32x4 acc[CT];
#pragma unroll
    for (int c = 0; c < CT; c++) acc[c] = {0.f, 0.f, 0.f, 0.f};

    for (int half = 0; half < (DUAL ? 2 : 1); half++) {
        const unsigned short* __restrict__ Bsrc = half ? Bp1 : Bp;
        const void* Asrc = half ? A1v : Av;
#pragma unroll
        for (int kb = 0; kb < 4; kb++) {
            short8 afr;
            if (AFP32) {
                const float* Af = (const float*)Asrc + (size_t)arow * 128 + kb * 32 + q * 8;
                float4 f0 = *(const float4*)Af;
                float4 f1 = *(const float4*)(Af + 4);
                afr[0] = (short)f2bf(f0.x); afr[1] = (short)f2bf(f0.y);
                afr[2] = (short)f2bf(f0.z); afr[3] = (short)f2bf(f0.w);
                afr[4] = (short)f2bf(f1.x); afr[5] = (short)f2bf(f1.y);
                afr[6] = (short)f2bf(f1.z); afr[7] = (short)f2bf(f1.w);
            } else {
                // channel-blocked bf16 [cb64][n][64]: cb = kb>>1
                afr = *(const short8*)((const unsigned short*)Asrc +
                                       ((size_t)(kb >> 1) * n + arow) * 64 +
                                       (kb & 1) * 32 + q * 8);
            }
            short8 bfr[CT];
#pragma unroll
            for (int c = 0; c < CT; c++)
                bfr[c] = *(const short8*)(Bsrc + ((size_t)(kb * CT + c) * 64 + lane) * 8);
#pragma unroll
            for (int c = 0; c < CT; c++)
                acc[c] = __builtin_amdgcn_mfma_f32_16x16x32_bf16(afr, bfr[c], acc[c], 0, 0, 0);
        }
    }

    if (DOTS) {
        float ps[4] = {0.f, 0.f, 0.f, 0.f}, pd[4] = {0.f, 0.f, 0.f, 0.f};
#pragma unroll
        for (int c = 0; c < CT; c++) {
            float sv = a_s[c * 16 + ml], dv = a_d[c * 16 + ml];
#pragma unroll
            for (int r = 0; r < 4; r++) {
                ps[r] = fmaf(acc[c][r], sv, ps[r]);
                pd[r] = fmaf(acc[c][r], dv, pd[r]);
            }
        }
#pragma unroll
        for (int off = 1; off < 16; off <<= 1) {
#pragma unroll
            for (int r = 0; r < 4; r++) {
                ps[r] += __shfl_xor(ps[r], off, 64);
                pd[r] += __shfl_xor(pd[r], off, 64);
            }
        }
        if (ml == 0) {
#pragma unroll
            for (int r = 0; r < 4; r++) {
                int row = row0 + q * 4 + r;
                if (row < n) { as_[row] = ps[r]; ad_[row] = pd[r]; }
            }
        }
    }

    float sc[4];
    if (SCALE) {
#pragma unroll
        for (int r = 0; r < 4; r++) {
            int row = row0 + q * 4 + r;
            sc[r] = scale[row < n ? row : 0];
        }
    }
#pragma unroll
    for (int c = 0; c < CT; c++) {
        float bv = BIASRELU ? bias[c * 16 + ml] : 0.0f;
        const int col = c * 16 + ml;
#pragma unroll
        for (int r = 0; r < 4; r++) {
            int row = row0 + q * 4 + r;
            if (row < n) {
                float v = acc[c][r];
                if (SCALE) v *= sc[r];
                if (BIASRELU) v = fmaxf(v + bv, 0.0f);
                C16[((size_t)(col >> 6) * n + row) * 64 + (col & 63)] = f2bf(v);
            }
        }
    }
}

// ---------------- CSR build: padded buckets (LDS atomics only) ----------------
#define PART_CH 4096
__global__ __launch_bounds__(256) void part_k(
    const int* __restrict__ src, const int* __restrict__ dst,
    int* __restrict__ bcur, unsigned long long* __restrict__ part, int nE)
{
    __shared__ int cnt[NBMAX];
    __shared__ int cur[NBMAX];
    const int base = blockIdx.x * PART_CH;
    const int t = threadIdx.x;
    cnt[t] = 0;
    __syncthreads();
    int d[PART_CH / 256], s[PART_CH / 256];
#pragma unroll
    for (int j = 0; j < PART_CH / 256; j++) {
        int e = base + j * 256 + t;
        if (e < nE) {
            d[j] = dst[e]; s[j] = src[e];
            atomicAdd(&cnt[d[j] >> BUCKET_BITS], 1);
        } else d[j] = -1;
    }
    __syncthreads();
    {
        int c = cnt[t];
        cur[t] = c ? atomicAdd(&bcur[t], c) : 0;
    }
    __syncthreads();
#pragma unroll
    for (int j = 0; j < PART_CH / 256; j++) {
        if (d[j] >= 0) {
            int p = atomicAdd(&cur[d[j] >> BUCKET_BITS], 1);
            part[p] = ((unsigned long long)(unsigned)d[j] << 32) | (unsigned)s[j];
        }
    }
}

// per-bucket CSR finalize; bucket-base scan inlined (196-entry LDS scan/block)
__global__ __launch_bounds__(256) void csr_k(
    const unsigned long long* __restrict__ part, const int* __restrict__ bcur,
    int* __restrict__ rowptr, int* __restrict__ srcs,
    float* __restrict__ dinv, float* __restrict__ invm, int n, int nE, int nb)
{
    __shared__ int lcnt[BUCKET_SZ];
    __shared__ int sm[BUCKET_SZ];
    __shared__ int lcur[BUCKET_SZ];
    const int b = blockIdx.x;
    const int t = threadIdx.x;
    const int base_in = b * CAP;
    const int cntE = bcur[b] - base_in;

    // inlined bucket scan: base_out = sum of counts of buckets < b
    int vb = (t < nb) ? (bcur[t] - t * CAP) : 0;
    sm[t] = vb;
    __syncthreads();
    for (int off = 1; off < 256; off <<= 1) {
        int tv = (t >= off) ? sm[t - off] : 0;
        __syncthreads();
        sm[t] += tv;
        __syncthreads();
    }
    const int base_out = sm[b] - (bcur[b] - b * CAP);
    __syncthreads();

    lcnt[t] = 0;
    __syncthreads();
#pragma unroll 4
    for (int e = t; e < cntE; e += 256) {
        int dl = (int)(part[base_in + e] >> 32) & (BUCKET_SZ - 1);
        atomicAdd(&lcnt[dl], 1);
    }
    __syncthreads();
    int v = lcnt[t];
    sm[t] = v;
    __syncthreads();
    for (int off = 1; off < 256; off <<= 1) {
        int tv = (t >= off) ? sm[t - off] : 0;
        __syncthreads();
        sm[t] += tv;
        __syncthreads();
    }
    const int excl = sm[t] - v;
    const int node = (b << BUCKET_BITS) + t;
    if (node < n) {
        rowptr[node] = base_out + excl;
        float dg = (float)v;
        dinv[node] = rsqrtf(dg + 1.0f);
        invm[node] = 1.0f / fmaxf(dg, 1.0f);
        if (node == n - 1) rowptr[n] = nE;
    }
    lcur[t] = excl;
    __syncthreads();
#pragma unroll 4
    for (int e = t; e < cntE; e += 256) {
        unsigned long long w = part[base_in + e];
        int dl = (int)(w >> 32) & (BUCKET_SZ - 1);
        int pos = atomicAdd(&lcur[dl], 1);
        srcs[base_out + pos] = (int)(unsigned)w;
    }
}

// ---------------- GAT edge-weight precompute: ew[e], rdn_[node], sw_[node] ----
__global__ __launch_bounds__(256) void gatw_k(
    const int* __restrict__ rowptr, const int* __restrict__ srcs,
    const float* __restrict__ as_, const float* __restrict__ ad_,
    float* __restrict__ ew, float* __restrict__ rdn_, float* __restrict__ sw_, int n)
{
    const int node = blockIdx.x * 32 + (threadIdx.x >> 3);
    const int lane = threadIdx.x & 7;
    if (node >= n) return;
    const int beg = rowptr[node], end = rowptr[node + 1];
    const float ad_d = ad_[node];
    float psum = 0.f;
    for (int k = beg + lane; k < end; k += 8) {
        float e = __expf(leaky02(as_[srcs[k]] + ad_d));
        ew[k] = e;
        psum += e;
    }
#pragma unroll
    for (int off = 4; off > 0; off >>= 1) psum += __shfl_xor(psum, off, 64);
    if (lane == 0) {
        float se = __expf(leaky02(as_[node] + ad_d));
        float r = 1.0f / (psum + se);
        rdn_[node] = r;
        sw_[node] = se * r;
    }
}

// ---------------- bf16 gather v21: 128B-row slices, 8 lanes/node --------------
// H channel-blocked [NCB][n][64] (NCB=2 for 128ch, NCB=1 for 64ch). Each edge
// read = one aligned 128B request (8 lanes x 16B). Block = 16 nodes (128 thr);
// slice pinned to XCDs via blockIdx%8. srcs/ew staged once into LDS.
// MODE 0: SAGE mean; 1: GCN relu; 2: GAT (precomputed ew/rden/sw); 3: GCN out.
template<int MODE, bool OV>
__device__ __forceinline__ void gath_loop(
    const char* __restrict__ Hb, unsigned loff,
    const int* __restrict__ srcs, const float* __restrict__ ew,
    const int* lsrc, const float* lw,
    int beg, int end, int beg_blk, f32x2* acc)
{
    int k = beg;
    for (; k + 16 <= end; k += 16) {
        int s[16]; float wv[16];
#pragma unroll
        for (int j = 0; j < 16; j++) {
            int ofs = k + j - beg_blk;
            if (OV) {
                bool in = ofs < CAPE;
                int ofc = in ? ofs : 0;
                s[j] = in ? lsrc[ofc] : srcs[k + j];
                if (MODE == 2) wv[j] = in ? lw[ofc] : ew[k + j];
            } else {
                s[j] = lsrc[ofs];
                if (MODE == 2) wv[j] = lw[ofs];
            }
        }
        u32x4 h[16];
#pragma unroll
        for (int j = 0; j < 16; j++)
            h[j] = *(const u32x4*)(Hb + (size_t)(((unsigned)s[j] << 7) + loff));
#pragma unroll
        for (int j = 0; j < 16; j++) {
            f32x2 w2 = {wv[j], wv[j]};
#pragma unroll
            for (int c = 0; c < 4; c++) {
                f32x2 hv = {bflo(h[j][c]), bfhi(h[j][c])};
                if (MODE == 2) acc[c] = w2 * hv + acc[c];   // v_pk_fma_f32
                else           acc[c] = acc[c] + hv;        // v_pk_add_f32
            }
        }
    }
    for (; k + 8 <= end; k += 8) {
        int s[8]; float wv[8];
#pragma unroll
        for (int j = 0; j < 8; j++) {
            int ofs = k + j - beg_blk;
            if (OV) {
                bool in = ofs < CAPE;
                int ofc = in ? ofs : 0;
                s[j] = in ? lsrc[ofc] : srcs[k + j];
                if (MODE == 2) wv[j] = in ? lw[ofc] : ew[k + j];
            } else {
                s[j] = lsrc[ofs];
                if (MODE == 2) wv[j] = lw[ofs];
            }
        }
        u32x4 h[8];
#pragma unroll
        for (int j = 0; j < 8; j++)
            h[j] = *(const u32x4*)(Hb + (size_t)(((unsigned)s[j] << 7) + loff));
#pragma unroll
        for (int j = 0; j < 8; j++) {
            f32x2 w2 = {wv[j], wv[j]};
#pragma unroll
            for (int c = 0; c < 4; c++) {
                f32x2 hv = {bflo(h[j][c]), bfhi(h[j][c])};
                if (MODE == 2) acc[c] = w2 * hv + acc[c];
                else           acc[c] = acc[c] + hv;
            }
        }
    }
    if (k < end) {
        // masked tail: idx clamped to valid edge, weight zeroed
        int s[8]; float wv[8];
#pragma unroll
        for (int j = 0; j < 8; j++) {
            int kk = k + j;
            bool act = kk < end;
            int kc = act ? kk : end - 1;
            int ofs = kc - beg_blk;
            int sj; float w0 = 1.0f;
            if (OV) {
                bool in = ofs < CAPE;
                int ofc = in ? ofs : 0;
                sj = in ? lsrc[ofc] : srcs[kc];
                if (MODE == 2) w0 = in ? lw[ofc] : ew[kc];
            } else {
                sj = lsrc[ofs];
                if (MODE == 2) w0 = lw[ofs];
            }
            s[j] = sj;
            wv[j] = act ? ((MODE == 2) ? w0 : 1.0f) : 0.0f;
        }
        u32x4 h[8];
#pragma unroll
        for (int j = 0; j < 8; j++)
            h[j] = *(const u32x4*)(Hb + (size_t)(((unsigned)s[j] << 7) + loff));
#pragma unroll
        for (int j = 0; j < 8; j++) {
            f32x2 w2 = {wv[j], wv[j]};
#pragma unroll
            for (int c = 0; c < 4; c++) {
                f32x2 hv = {bflo(h[j][c]), bfhi(h[j][c])};
                acc[c] = w2 * hv + acc[c];
            }
        }
    }
}

template<int NCB, int MODE>
__global__ __launch_bounds__(128, 4) void gatherbf_k(
    const unsigned short* __restrict__ H16, float* __restrict__ outf,
    unsigned short* __restrict__ out16,
    const int* __restrict__ rowptr, const int* __restrict__ srcs,
    const float* __restrict__ scl,   // MODE0: invm; MODE1/3: dinv; MODE2: rdn_
    const float* __restrict__ sw_,   // MODE2: self-alpha
    const float* __restrict__ ew,    // MODE2: per-edge exp weights
    const float* __restrict__ bias, int n)
{
    constexpr int XPC = 8 / NCB;     // XCDs per channel-slice
    constexpr int NPB = 16;          // nodes per block
    __shared__ int lsrc[CAPE];
    __shared__ float lw[(MODE == 2) ? CAPE : 1];

    const int bid = (int)blockIdx.x;
    const int xj = bid & 7;
    const int cb = xj / XPC;
    const int NG = (n + NPB - 1) / NPB;
    const int ng = (bid >> 3) * XPC + (xj % XPC);
    if (ng >= NG) return;

    const int tid = (int)threadIdx.x;
    const int node0 = ng * NPB;
    const int nodeN = min(node0 + NPB, n);
    const int beg_blk = rowptr[node0];
    const int end_blk = rowptr[nodeN];
    const int cnt = end_blk - beg_blk;
    const int cl = min(cnt, CAPE);
    for (int i = tid; i < cl; i += 128) {
        lsrc[i] = srcs[beg_blk + i];
        if (MODE == 2) lw[i] = ew[beg_blk + i];
    }
    __syncthreads();

    const int node = node0 + (tid >> 3);
    const int lane = tid & 7;
    if (node >= nodeN) return;
    const int beg = rowptr[node], end = rowptr[node + 1];
    const char* __restrict__ Hb = (const char*)H16 + (size_t)cb * n * 128;
    const unsigned loff = (unsigned)lane * 16u;

    f32x2 acc[4];
#pragma unroll
    for (int c = 0; c < 4; c++) acc[c] = {0.f, 0.f};

    if (cnt <= CAPE)
        gath_loop<MODE, false>(Hb, loff, srcs, ew, lsrc, lw, beg, end, beg_blk, acc);
    else
        gath_loop<MODE, true>(Hb, loff, srcs, ew, lsrc, lw, beg, end, beg_blk, acc);

    const size_t orow = ((size_t)cb * n + node) * 8 + lane;   // u16x8 units
    float r[8];
    if (MODE == 0) {
        float sc = scl[node];
#pragma unroll
        for (int c = 0; c < 4; c++) { r[2*c] = acc[c].x * sc; r[2*c+1] = acc[c].y * sc; }
    } else {
        u32x4 su = *(const u32x4*)(Hb + (size_t)(((unsigned)node << 7) + loff));
        float sv[8];
#pragma unroll
        for (int c = 0; c < 4; c++) { sv[2*c] = bflo(su[c]); sv[2*c+1] = bfhi(su[c]); }
        const float4* b4 = (const float4*)bias;
        float4 ba = b4[cb * 16 + lane * 2], bb = b4[cb * 16 + lane * 2 + 1];
        float bv[8] = {ba.x, ba.y, ba.z, ba.w, bb.x, bb.y, bb.z, bb.w};
        float a8[8];
#pragma unroll
        for (int c = 0; c < 4; c++) { a8[2*c] = acc[c].x; a8[2*c+1] = acc[c].y; }
        if (MODE == 2) {
            float rden = scl[node], sw = sw_[node];
#pragma unroll
            for (int j = 0; j < 8; j++)
                r[j] = fmaxf(fmaf(rden, a8[j], fmaf(sw, sv[j], bv[j])), 0.f);
        } else {
            float dv = scl[node];
#pragma unroll
            for (int j = 0; j < 8; j++) {
                r[j] = dv * (a8[j] + sv[j]) + bv[j];
                if (MODE == 1) r[j] = fmaxf(r[j], 0.f);
            }
        }
    }
    if (MODE == 3) {
        float4* o4 = (float4*)(outf + (size_t)node * 64 + lane * 8);
        float4 ra = {r[0], r[1], r[2], r[3]}, rb = {r[4], r[5], r[6], r[7]};
        o4[0] = ra; o4[1] = rb;
    } else {
        u16x8 qv;
#pragma unroll
        for (int j = 0; j < 8; j++) qv[j] = f2bf(r[j]);
        ((u16x8*)out16)[orow] = qv;
    }
}

// ---------------------------------------------------------------------------
extern "C" void kernel_launch(void* const* d_in, const int* in_sizes, int n_in,
                              void* d_out, int out_size, void* d_ws, size_t ws_size,
                              hipStream_t stream)
{
    const float* x   = (const float*)d_in[0];
    const int*   ei  = (const int*)d_in[1];
    const float* W1  = (const float*)d_in[2];
    const float* b1  = (const float*)d_in[3];
    const float* Wl  = (const float*)d_in[4];
    const float* Wr  = (const float*)d_in[5];
    const float* bs  = (const float*)d_in[6];
    const float* Wg  = (const float*)d_in[7];
    const float* a_s = (const float*)d_in[8];
    const float* a_d = (const float*)d_in[9];
    const float* bg  = (const float*)d_in[10];
    const float* Wo  = (const float*)d_in[11];
    const float* bo  = (const float*)d_in[12];

    const int n  = in_sizes[0] / 128;
    const int nE = in_sizes[1] / 2;
    const int* src = ei;
    const int* dst = ei + nE;

    char* w = (char*)d_ws;
    auto alloc = [&](size_t bytes) { char* p = w; w += (bytes + 255) & ~(size_t)255; return p; };
    unsigned short* S0 = (unsigned short*)alloc((size_t)n * 128 * 2);
    unsigned short* S1 = (unsigned short*)alloc((size_t)n * 128 * 2);
    unsigned short* S2 = (unsigned short*)alloc((size_t)n * 128 * 2);
    const int nbv = (n + BUCKET_SZ - 1) / BUCKET_SZ;
    unsigned long long* part = (unsigned long long*)alloc((size_t)nbv * CAP * 8);
    int*   srcs   = (int*)alloc((size_t)nE * 4);
    float* ew     = (float*)alloc((size_t)nE * 4);
    int*   rowptr = (int*)alloc((size_t)(n + 1) * 4);
    int*   bcur   = (int*)alloc(NBMAX * 4);
    float* dinv   = (float*)alloc((size_t)n * 4);
    float* invm   = (float*)alloc((size_t)n * 4);
    float* as_    = (float*)alloc((size_t)n * 4);
    float* ad_    = (float*)alloc((size_t)n * 4);
    float* rdn_   = (float*)alloc((size_t)n * 4);
    float* sw_    = (float*)alloc((size_t)n * 4);
    unsigned* P1  = (unsigned*)alloc(64 * 128 * 4);
    unsigned* Pl  = (unsigned*)alloc(64 * 128 * 4);
    unsigned* Pr  = (unsigned*)alloc(64 * 128 * 4);
    unsigned* Pg  = (unsigned*)alloc(64 * 128 * 4);
    unsigned* Po  = (unsigned*)alloc(64 * 64 * 4);

    const int TB = 256;
    auto cdiv = [](long long a, long long b) { return (int)((a + b - 1) / b); };
    const int nb     = nbv;
    const int gPart  = cdiv(nE, PART_CH);
    const int gGemm  = cdiv(n, 64);
    const int NG     = cdiv(n, 16);            // node-groups of 16
    const int gGa128 = 8 * cdiv(NG, 4);        // NCB=2, 4 XCDs per slice
    const int gGa64  = 8 * cdiv(NG, 8);        // NCB=1, 8 XCDs
    const int gGatw  = cdiv(n, 32);

    // ---- weight pre-pack + bucket init (1 dispatch) + bucket CSR build
    wpackall_k<<<6, TB, 0, stream>>>(W1, Wl, Wr, Wg, Wo, P1, Pl, Pr, Pg, Po, bcur, nb);
    part_k<<<gPart, TB, 0, stream>>>(src, dst, bcur, part, nE);
    csr_k<<<nb, TB, 0, stream>>>(part, bcur, rowptr, srcs, dinv, invm, n, nE, nb);

    // ---- Layer 1: GCN — x@W1 scaled by dinv[row] -> S0; gather -> S1 (=h1)
    mgemm_k<128, true, true, false, false, false><<<gGemm, TB, 0, stream>>>(
        x, (const unsigned short*)P1, nullptr, nullptr, S0, dinv, nullptr,
        nullptr, nullptr, nullptr, nullptr, n);
    gatherbf_k<2, 1><<<gGa128, 128, 0, stream>>>(S0, nullptr, S1, rowptr, srcs,
                                                 dinv, nullptr, nullptr, b1, n);

    // ---- Layer 2: SAGE — mean(S1) -> S0; dual GEMM mean@Wl + h1@Wr -> S2 (=h2)
    gatherbf_k<2, 0><<<gGa128, 128, 0, stream>>>(S1, nullptr, S0, rowptr, srcs,
                                                 invm, nullptr, nullptr, nullptr, n);
    mgemm_k<128, false, false, true, true, false><<<gGemm, TB, 0, stream>>>(
        S0, (const unsigned short*)Pl, S1, (const unsigned short*)Pr, S2,
        nullptr, bs, nullptr, nullptr, nullptr, nullptr, n);

    // ---- Layer 3: GAT — h2@Wg -> S1 (+fused dots); edge weights; gather -> S0
    mgemm_k<128, false, false, false, false, true><<<gGemm, TB, 0, stream>>>(
        S2, (const unsigned short*)Pg, nullptr, nullptr, S1, nullptr, nullptr,
        a_s, a_d, as_, ad_, n);
    gatw_k<<<gGatw, TB, 0, stream>>>(rowptr, srcs, as_, ad_, ew, rdn_, sw_, n);
    gatherbf_k<2, 2><<<gGa128, 128, 0, stream>>>(S1, nullptr, S0, rowptr, srcs,
                                                 rdn_, sw_, ew, bg, n);

    // ---- Output: h3@Wo scaled by dinv[row] -> S2 ([N][64]); gather -> d_out
    mgemm_k<64, false, true, false, false, false><<<gGemm, TB, 0, stream>>>(
        S0, (const unsigned short*)Po, nullptr, nullptr, S2, dinv, nullptr,
        nullptr, nullptr, nullptr, nullptr, n);
    gatherbf_k<1, 3><<<gGa64, 128, 0, stream>>>(S2, (float*)d_out, nullptr, rowptr, srcs,
                                                dinv, nullptr, nullptr, bo, n);
}